// Round 2
// baseline (931.108 us; speedup 1.0000x reference)
//
#include <hip/hip_runtime.h>
#include <hip/hip_bf16.h>
#include <math.h>
#include <stdint.h>

typedef __bf16 bf16;
typedef __attribute__((ext_vector_type(8))) __bf16 bf16x8;
typedef __attribute__((ext_vector_type(4))) __bf16 bf16x4;
typedef __attribute__((ext_vector_type(4))) float f32x4;

// problem dims
static constexpr int cB = 2, cS = 2048, cCTX = 256, cD = 1024, cH = 16, cDH = 64, cDFF = 4096;

// ---------------- transpose+convert: fp32 [K,N] -> bf16 [N,K], 64x64 tiles ----------------
__global__ __launch_bounds__(256) void k_transpose(const float* __restrict__ in,
                                                   bf16* __restrict__ out, int K, int N) {
  __shared__ bf16 tile[64][66];  // +2 pad breaks bank conflicts on transposed read
  const int n0 = blockIdx.x * 64, k0 = blockIdx.y * 64;
  const int t = threadIdx.x;
  const int r = t >> 2, cb = (t & 3) * 16;
  const float* src = in + (size_t)(k0 + r) * N + n0 + cb;
#pragma unroll
  for (int q4 = 0; q4 < 4; ++q4) {
    f32x4 v = *(const f32x4*)(src + q4 * 4);
#pragma unroll
    for (int e = 0; e < 4; ++e) tile[r][cb + q4 * 4 + e] = (bf16)v[e];
  }
  __syncthreads();
  bf16* dst = out + (size_t)(n0 + r) * K + k0 + cb;
  bf16x8 o0, o1;
#pragma unroll
  for (int e = 0; e < 8; ++e) { o0[e] = tile[cb + e][r]; o1[e] = tile[cb + 8 + e][r]; }
  *(bf16x8*)(dst) = o0;
  *(bf16x8*)(dst + 8) = o1;
}

// ---------------- fp32 -> bf16 elementwise convert ----------------
__global__ __launch_bounds__(256) void k_f2b(const float* __restrict__ in, bf16* __restrict__ out) {
  const int base = (blockIdx.x * 256 + threadIdx.x) * 4;
  f32x4 v = *(const f32x4*)(in + base);
  bf16x4 o;
#pragma unroll
  for (int e = 0; e < 4; ++e) o[e] = (bf16)v[e];
  *(bf16x4*)(out + base) = o;
}

// ---------------- emb = t @ W + b  (t:[2,1024] fp32, W:[1024,2048] fp32) -> fp32 [2,2048] ----------------
__global__ __launch_bounds__(256) void k_emb(const float* __restrict__ t,
                                             const float* __restrict__ w,
                                             const float* __restrict__ bias,
                                             float* __restrict__ emb) {
  const int jj = threadIdx.x & 63;
  const int j = blockIdx.x * 64 + jj;
  const int kg = threadIdx.x >> 6;
  float a0 = 0.f, a1 = 0.f;
  for (int k = kg * 256; k < kg * 256 + 256; ++k) {
    float wv = w[(size_t)k * 2048 + j];
    a0 += t[k] * wv;
    a1 += t[1024 + k] * wv;
  }
  __shared__ float s0[4][64], s1[4][64];
  s0[kg][jj] = a0;
  s1[kg][jj] = a1;
  __syncthreads();
  if (threadIdx.x < 64) {
    emb[j] = s0[0][jj] + s0[1][jj] + s0[2][jj] + s0[3][jj] + bias[j];
    emb[2048 + j] = s1[0][jj] + s1[1][jj] + s1[2][jj] + s1[3][jj] + bias[j];
  }
}

// ---------------- AdaLN: h = LN(xres) * (1+scale) + shift, bf16 out ----------------
__global__ __launch_bounds__(256) void k_adaln(const float* __restrict__ xres,
                                               const float* __restrict__ emb,
                                               bf16* __restrict__ h) {
  const int token = blockIdx.x;          // B*S = 4096
  const int b = token >> 11;             // S = 2048
  const float* x = xres + (size_t)token * 1024;
  const float* sc = emb + b * 2048;      // [scale(1024) | shift(1024)]
  const int t = threadIdx.x;
  float v[4], s = 0.f, sq = 0.f;
#pragma unroll
  for (int i = 0; i < 4; ++i) {
    float u = x[t + 256 * i];
    v[i] = u; s += u; sq += u * u;
  }
#pragma unroll
  for (int off = 1; off < 64; off <<= 1) {
    s += __shfl_xor(s, off);
    sq += __shfl_xor(sq, off);
  }
  __shared__ float ss[4], ssq[4];
  const int wave = t >> 6;
  if ((t & 63) == 0) { ss[wave] = s; ssq[wave] = sq; }
  __syncthreads();
  const float S_ = ss[0] + ss[1] + ss[2] + ss[3];
  const float SQ = ssq[0] + ssq[1] + ssq[2] + ssq[3];
  const float mean = S_ * (1.f / 1024.f);
  const float var = SQ * (1.f / 1024.f) - mean * mean;
  const float rstd = rsqrtf(var + 1e-5f);
#pragma unroll
  for (int i = 0; i < 4; ++i) {
    const int c = t + 256 * i;
    float val = (v[i] - mean) * rstd * (1.f + sc[c]) + sc[1024 + c];
    h[(size_t)token * 1024 + c] = (bf16)val;
  }
}

// ---------------- GEMM: C[M,N] = A[M,K] @ Bt[N,K]^T (+bias fp32)(+fp32 res) ----------------
// m93 structure: 128x128 tile, 4 waves, 4x4 16x16x32 MFMA subtiles each, BK=32.
__global__ __launch_bounds__(256) void k_gemm(const bf16* __restrict__ A,
                                              const bf16* __restrict__ Bt,
                                              bf16* Cb, float* Cf,
                                              const float* __restrict__ bias,
                                              const float* res,  // may alias Cf (no restrict)
                                              int M, int N, int K) {
  __shared__ bf16 As[128 * 32];
  __shared__ bf16 Bs[128 * 32];
  const int m0 = blockIdx.y * 128, n0 = blockIdx.x * 128;
  const int tid = threadIdx.x;
  const int wave = tid >> 6, lane = tid & 63;
  const int quad = lane >> 4, l16 = lane & 15;
  const int mw = (wave >> 1) * 64, nw = (wave & 1) * 64;
  f32x4 acc[4][4];
#pragma unroll
  for (int i = 0; i < 4; ++i)
#pragma unroll
    for (int j = 0; j < 4; ++j) acc[i][j] = (f32x4){0.f, 0.f, 0.f, 0.f};

  const int r0 = tid >> 2;           // staging row (0..63), +64 on second chunk
  const int c0 = (tid & 3) << 3;     // staging col {0,8,16,24}

  for (int k0 = 0; k0 < K; k0 += 32) {
    __syncthreads();
#pragma unroll
    for (int i = 0; i < 2; ++i) {
      const int row = r0 + i * 64;
      *(bf16x8*)(As + row * 32 + c0) = *(const bf16x8*)(A + (size_t)(m0 + row) * K + k0 + c0);
      *(bf16x8*)(Bs + row * 32 + c0) = *(const bf16x8*)(Bt + (size_t)(n0 + row) * K + k0 + c0);
    }
    __syncthreads();
    bf16x8 af[4], bfr[4];
#pragma unroll
    for (int i = 0; i < 4; ++i)
      af[i] = *(const bf16x8*)(As + (mw + i * 16 + l16) * 32 + quad * 8);
#pragma unroll
    for (int j = 0; j < 4; ++j)
      bfr[j] = *(const bf16x8*)(Bs + (nw + j * 16 + l16) * 32 + quad * 8);
#pragma unroll
    for (int i = 0; i < 4; ++i)
#pragma unroll
      for (int j = 0; j < 4; ++j)
        acc[i][j] = __builtin_amdgcn_mfma_f32_16x16x32_bf16(af[i], bfr[j], acc[i][j], 0, 0, 0);
  }

  // epilogue: C/D layout row = quad*4+r, col = l16 within each 16x16 tile
#pragma unroll
  for (int i = 0; i < 4; ++i) {
    const int rbase = m0 + mw + i * 16 + quad * 4;
#pragma unroll
    for (int j = 0; j < 4; ++j) {
      const int col = n0 + nw + j * 16 + l16;
      const float bv = bias ? bias[col] : 0.f;
#pragma unroll
      for (int r = 0; r < 4; ++r) {
        const size_t off = (size_t)(rbase + r) * N + col;
        float v2 = acc[i][j][r] + bv;
        if (res) v2 += res[off];
        if (Cf) Cf[off] = v2;
        if (Cb) Cb[off] = (bf16)v2;
      }
    }
  }
}

// ---------------- FF1 GEMM with fused GLU: g = (h@W1a + b1a) * gelu(h@W1g + b1g) ----------------
// Bt = ff_w1^T [8192,1024] bf16; rows [0,4096) = a-half, [4096,8192) = gate-half.
__global__ __launch_bounds__(256) void k_gemm_glu(const bf16* __restrict__ A,
                                                  const bf16* __restrict__ Bt,
                                                  const float* __restrict__ bias,
                                                  bf16* __restrict__ Cb,
                                                  int M, int N, int K) {
  __shared__ bf16 As[128 * 32];
  __shared__ bf16 Ba[64 * 32];
  __shared__ bf16 Bg[64 * 32];
  const int m0 = blockIdx.y * 128, n0 = blockIdx.x * 64;
  const int tid = threadIdx.x;
  const int wave = tid >> 6, lane = tid & 63;
  const int quad = lane >> 4, l16 = lane & 15;
  const int mw = (wave >> 1) * 64, nw = (wave & 1) * 32;
  f32x4 aa[4][2], ag[4][2];
#pragma unroll
  for (int i = 0; i < 4; ++i)
#pragma unroll
    for (int j = 0; j < 2; ++j) {
      aa[i][j] = (f32x4){0.f, 0.f, 0.f, 0.f};
      ag[i][j] = (f32x4){0.f, 0.f, 0.f, 0.f};
    }

  const int r0 = tid >> 2;
  const int c0 = (tid & 3) << 3;

  for (int k0 = 0; k0 < K; k0 += 32) {
    __syncthreads();
#pragma unroll
    for (int i = 0; i < 2; ++i) {
      const int row = r0 + i * 64;
      *(bf16x8*)(As + row * 32 + c0) = *(const bf16x8*)(A + (size_t)(m0 + row) * K + k0 + c0);
    }
    *(bf16x8*)(Ba + r0 * 32 + c0) = *(const bf16x8*)(Bt + (size_t)(n0 + r0) * K + k0 + c0);
    *(bf16x8*)(Bg + r0 * 32 + c0) = *(const bf16x8*)(Bt + (size_t)(N + n0 + r0) * K + k0 + c0);
    __syncthreads();
    bf16x8 af[4], ba[2], bg[2];
#pragma unroll
    for (int i = 0; i < 4; ++i)
      af[i] = *(const bf16x8*)(As + (mw + i * 16 + l16) * 32 + quad * 8);
#pragma unroll
    for (int j = 0; j < 2; ++j) {
      ba[j] = *(const bf16x8*)(Ba + (nw + j * 16 + l16) * 32 + quad * 8);
      bg[j] = *(const bf16x8*)(Bg + (nw + j * 16 + l16) * 32 + quad * 8);
    }
#pragma unroll
    for (int i = 0; i < 4; ++i)
#pragma unroll
      for (int j = 0; j < 2; ++j) {
        aa[i][j] = __builtin_amdgcn_mfma_f32_16x16x32_bf16(af[i], ba[j], aa[i][j], 0, 0, 0);
        ag[i][j] = __builtin_amdgcn_mfma_f32_16x16x32_bf16(af[i], bg[j], ag[i][j], 0, 0, 0);
      }
  }

#pragma unroll
  for (int i = 0; i < 4; ++i) {
    const int rbase = m0 + mw + i * 16 + quad * 4;
#pragma unroll
    for (int j = 0; j < 2; ++j) {
      const int col = n0 + nw + j * 16 + l16;
      const float ba_v = bias[col];
      const float bg_v = bias[N + col];
#pragma unroll
      for (int r = 0; r < 4; ++r) {
        float av = aa[i][j][r] + ba_v;
        float gv = ag[i][j][r] + bg_v;
        float ge = 0.5f * gv * (1.0f + erff(gv * 0.70710678118654752f));  // exact gelu
        Cb[(size_t)(rbase + r) * N + col] = (bf16)(av * ge);
      }
    }
  }
}

// ---------------- flash attention: O = softmax(Q K^T / 8) V ----------------
// Q:[B*S, H*DH] rows b*S+s; K/V:[B*kvlen, H*DH] rows b*kvlen+s. 64 Q-rows/block (16/wave).
__global__ __launch_bounds__(256) void k_attn(const bf16* __restrict__ Qp,
                                              const bf16* __restrict__ Kp,
                                              const bf16* __restrict__ Vp,
                                              bf16* __restrict__ Op, int kvlen) {
  const int qt = blockIdx.x * 64;
  const int hd = blockIdx.y;
  const int b = blockIdx.z;
  const int tid = threadIdx.x;
  const int wave = tid >> 6, lane = tid & 63;
  const int quad = lane >> 4, l16 = lane & 15;

  __shared__ bf16 Ks[64 * 64];      // [key][d]
  __shared__ bf16 Vs[64 * 64];      // [d][key]  (transposed for PV B-frags)
  __shared__ bf16 Ps[4][16 * 64];   // per-wave P round-trip [qrow][key]

  // Q A-fragments, 1/sqrt(DH)=0.125 folded in (exact: power of two)
  const bf16* qrow = Qp + (size_t)(b * cS + qt + wave * 16 + l16) * 1024 + hd * 64;
  bf16x8 qf[2];
#pragma unroll
  for (int c = 0; c < 2; ++c) {
    bf16x8 raw = *(const bf16x8*)(qrow + c * 32 + quad * 8);
#pragma unroll
    for (int e = 0; e < 8; ++e) qf[c][e] = (bf16)((float)raw[e] * 0.125f);
  }

  float m_i[4], l_i[4];
  f32x4 o_acc[4];
#pragma unroll
  for (int r = 0; r < 4; ++r) { m_i[r] = -1e30f; l_i[r] = 0.f; }
#pragma unroll
  for (int n = 0; n < 4; ++n) o_acc[n] = (f32x4){0.f, 0.f, 0.f, 0.f};

  const int srow_stage = tid >> 2, scb = (tid & 3) * 16;

  for (int kt = 0; kt < kvlen; kt += 64) {
    __syncthreads();
    {  // stage K [key][d] and V^T [d][key]
      const bf16* srck = Kp + (size_t)(b * kvlen + kt + srow_stage) * 1024 + hd * 64 + scb;
      bf16x8 v0 = *(const bf16x8*)(srck);
      bf16x8 v1 = *(const bf16x8*)(srck + 8);
      *(bf16x8*)(Ks + srow_stage * 64 + scb) = v0;
      *(bf16x8*)(Ks + srow_stage * 64 + scb + 8) = v1;
      const bf16* srcv = Vp + (size_t)(b * kvlen + kt + srow_stage) * 1024 + hd * 64 + scb;
      bf16x8 w0 = *(const bf16x8*)(srcv);
      bf16x8 w1 = *(const bf16x8*)(srcv + 8);
#pragma unroll
      for (int e = 0; e < 8; ++e) {
        Vs[(scb + e) * 64 + srow_stage] = w0[e];
        Vs[(scb + 8 + e) * 64 + srow_stage] = w1[e];
      }
    }
    __syncthreads();

    // scores: 4 key sub-tiles of 16
    f32x4 s[4];
#pragma unroll
    for (int t = 0; t < 4; ++t) {
      f32x4 accs = (f32x4){0.f, 0.f, 0.f, 0.f};
#pragma unroll
      for (int c = 0; c < 2; ++c) {
        bf16x8 kf = *(const bf16x8*)(Ks + (t * 16 + l16) * 64 + c * 32 + quad * 8);
        accs = __builtin_amdgcn_mfma_f32_16x16x32_bf16(qf[c], kf, accs, 0, 0, 0);
      }
      s[t] = accs;
    }

    // online softmax (rows quad*4+r; reduce over 16 lanes of the quad)
    float alpha[4];
#pragma unroll
    for (int r = 0; r < 4; ++r) {
      float v = fmaxf(fmaxf(s[0][r], s[1][r]), fmaxf(s[2][r], s[3][r]));
      v = fmaxf(v, __shfl_xor(v, 1));
      v = fmaxf(v, __shfl_xor(v, 2));
      v = fmaxf(v, __shfl_xor(v, 4));
      v = fmaxf(v, __shfl_xor(v, 8));
      const float mn = fmaxf(m_i[r], v);
      alpha[r] = __expf(m_i[r] - mn);
      m_i[r] = mn;
    }
#pragma unroll
    for (int t = 0; t < 4; ++t)
#pragma unroll
      for (int r = 0; r < 4; ++r) {
        float p = __expf(s[t][r] - m_i[r]);
        s[t][r] = p;
        Ps[wave][(quad * 4 + r) * 64 + t * 16 + l16] = (bf16)p;
      }
#pragma unroll
    for (int r = 0; r < 4; ++r) {
      float v = s[0][r] + s[1][r] + s[2][r] + s[3][r];
      v += __shfl_xor(v, 1);
      v += __shfl_xor(v, 2);
      v += __shfl_xor(v, 4);
      v += __shfl_xor(v, 8);
      l_i[r] = l_i[r] * alpha[r] + v;
    }
#pragma unroll
    for (int n = 0; n < 4; ++n)
#pragma unroll
      for (int r = 0; r < 4; ++r) o_acc[n][r] *= alpha[r];

    // PV: P back from LDS in A-layout, V^T B-frags
    bf16x8 pf[2];
#pragma unroll
    for (int c = 0; c < 2; ++c)
      pf[c] = *(const bf16x8*)(&Ps[wave][l16 * 64 + c * 32 + quad * 8]);
#pragma unroll
    for (int n = 0; n < 4; ++n)
#pragma unroll
      for (int c = 0; c < 2; ++c) {
        bf16x8 vf = *(const bf16x8*)(Vs + (n * 16 + l16) * 64 + c * 32 + quad * 8);
        o_acc[n] = __builtin_amdgcn_mfma_f32_16x16x32_bf16(pf[c], vf, o_acc[n], 0, 0, 0);
      }
  }

#pragma unroll
  for (int n = 0; n < 4; ++n)
#pragma unroll
    for (int r = 0; r < 4; ++r) {
      const int srow = qt + wave * 16 + quad * 4 + r;
      const int d = n * 16 + l16;
      Op[(size_t)(b * cS + srow) * 1024 + hd * 64 + d] = (bf16)(o_acc[n][r] / l_i[r]);
    }
}

// ---------------- launch ----------------
extern "C" void kernel_launch(void* const* d_in, const int* in_sizes, int n_in,
                              void* d_out, int out_size, void* d_ws, size_t ws_size,
                              hipStream_t stream) {
  // ALL reference inputs are float32
  const float* x    = (const float*)d_in[0];
  const float* tt   = (const float*)d_in[1];
  const float* ctx  = (const float*)d_in[2];
  const float* a1wq = (const float*)d_in[3];
  const float* a1wk = (const float*)d_in[4];
  const float* a1wv = (const float*)d_in[5];
  const float* a1wo = (const float*)d_in[6];
  const float* a1bo = (const float*)d_in[7];
  const float* a2wq = (const float*)d_in[8];
  const float* a2wk = (const float*)d_in[9];
  const float* a2wv = (const float*)d_in[10];
  const float* a2wo = (const float*)d_in[11];
  const float* a2bo = (const float*)d_in[12];
  const float* fw1  = (const float*)d_in[13];
  const float* fb1  = (const float*)d_in[14];
  const float* fw2  = (const float*)d_in[15];
  const float* fb2  = (const float*)d_in[16];
  const float* n1w  = (const float*)d_in[17];
  const float* n1b  = (const float*)d_in[18];
  const float* n2w  = (const float*)d_in[19];
  const float* n2b  = (const float*)d_in[20];
  const float* n3w  = (const float*)d_in[21];
  const float* n3b  = (const float*)d_in[22];

  char* ws = (char*)d_ws;
  const size_t MB = 1ull << 20;
  // ws layout (~97 MB total)
  bf16* wtq1 = (bf16*)(ws + 0 * MB);
  bf16* wtk1 = (bf16*)(ws + 2 * MB);
  bf16* wtv1 = (bf16*)(ws + 4 * MB);
  bf16* wto1 = (bf16*)(ws + 6 * MB);
  bf16* wtq2 = (bf16*)(ws + 8 * MB);
  bf16* wtk2 = (bf16*)(ws + 10 * MB);
  bf16* wtv2 = (bf16*)(ws + 12 * MB);
  bf16* wto2 = (bf16*)(ws + 14 * MB);
  bf16* wtf1 = (bf16*)(ws + 16 * MB);   // [8192,1024] bf16, 16 MB
  bf16* wtf2 = (bf16*)(ws + 32 * MB);   // [1024,4096] bf16, 8 MB
  float* emb1 = (float*)(ws + 40 * MB);
  float* emb2 = (float*)(ws + 40 * MB + 65536);
  float* emb3 = (float*)(ws + 40 * MB + 131072);
  bf16* ctxb = (bf16*)(ws + 40 * MB + 524288);  // [512,1024] bf16, 1 MB
  float* xres = (float*)(ws + 41 * MB + 524288); // fp32 residual stream, 16 MB
  bf16* h    = (bf16*)(ws + 58 * MB);   // normed activations, 8 MB
  bf16* q    = (bf16*)(ws + 66 * MB);
  bf16* kk   = (bf16*)(ws + 74 * MB);
  bf16* vv   = (bf16*)(ws + 82 * MB);
  bf16* ao   = (bf16*)(ws + 90 * MB);
  bf16* g    = (bf16*)(ws + 66 * MB);   // FFN intermediate aliases dead attn buffers
  float* out = (float*)d_out;           // output is float32

  const dim3 blk(256);

  // weight transpose+convert fp32 [K,N] -> bf16 [N,K]
  k_transpose<<<dim3(16, 16), blk, 0, stream>>>(a1wq, wtq1, 1024, 1024);
  k_transpose<<<dim3(16, 16), blk, 0, stream>>>(a1wk, wtk1, 1024, 1024);
  k_transpose<<<dim3(16, 16), blk, 0, stream>>>(a1wv, wtv1, 1024, 1024);
  k_transpose<<<dim3(16, 16), blk, 0, stream>>>(a1wo, wto1, 1024, 1024);
  k_transpose<<<dim3(16, 16), blk, 0, stream>>>(a2wq, wtq2, 1024, 1024);
  k_transpose<<<dim3(16, 16), blk, 0, stream>>>(a2wk, wtk2, 1024, 1024);
  k_transpose<<<dim3(16, 16), blk, 0, stream>>>(a2wv, wtv2, 1024, 1024);
  k_transpose<<<dim3(16, 16), blk, 0, stream>>>(a2wo, wto2, 1024, 1024);
  k_transpose<<<dim3(128, 16), blk, 0, stream>>>(fw1, wtf1, 1024, 8192);
  k_transpose<<<dim3(16, 64), blk, 0, stream>>>(fw2, wtf2, 4096, 1024);

  // AdaLN emb GEMMs (fp32) + ctx bf16 convert
  k_emb<<<32, blk, 0, stream>>>(tt, n1w, n1b, emb1);
  k_emb<<<32, blk, 0, stream>>>(tt, n2w, n2b, emb2);
  k_emb<<<32, blk, 0, stream>>>(tt, n3w, n3b, emb3);
  k_f2b<<<512, blk, 0, stream>>>(ctx, ctxb);

  // ---- block 1: self-attention (x is the fp32 residual directly) ----
  k_adaln<<<4096, blk, 0, stream>>>(x, emb1, h);
  k_gemm<<<dim3(8, 32), blk, 0, stream>>>(h, wtq1, q, nullptr, nullptr, nullptr, 4096, 1024, 1024);
  k_gemm<<<dim3(8, 32), blk, 0, stream>>>(h, wtk1, kk, nullptr, nullptr, nullptr, 4096, 1024, 1024);
  k_gemm<<<dim3(8, 32), blk, 0, stream>>>(h, wtv1, vv, nullptr, nullptr, nullptr, 4096, 1024, 1024);
  k_attn<<<dim3(32, 16, 2), blk, 0, stream>>>(q, kk, vv, ao, 2048);
  k_gemm<<<dim3(8, 32), blk, 0, stream>>>(ao, wto1, nullptr, xres, a1bo, x, 4096, 1024, 1024);

  // ---- block 2: cross-attention ----
  k_adaln<<<4096, blk, 0, stream>>>(xres, emb2, h);
  k_gemm<<<dim3(8, 32), blk, 0, stream>>>(h, wtq2, q, nullptr, nullptr, nullptr, 4096, 1024, 1024);
  k_gemm<<<dim3(8, 4), blk, 0, stream>>>(ctxb, wtk2, kk, nullptr, nullptr, nullptr, 512, 1024, 1024);
  k_gemm<<<dim3(8, 4), blk, 0, stream>>>(ctxb, wtv2, vv, nullptr, nullptr, nullptr, 512, 1024, 1024);
  k_attn<<<dim3(32, 16, 2), blk, 0, stream>>>(q, kk, vv, ao, 256);
  k_gemm<<<dim3(8, 32), blk, 0, stream>>>(ao, wto2, nullptr, xres, a2bo, xres, 4096, 1024, 1024);

  // ---- block 3: gated-GELU FFN ----
  k_adaln<<<4096, blk, 0, stream>>>(xres, emb3, h);
  k_gemm_glu<<<dim3(64, 32), blk, 0, stream>>>(h, wtf1, fb1, g, 4096, 4096, 1024);
  k_gemm<<<dim3(8, 32), blk, 0, stream>>>(g, wtf2, nullptr, out, fb2, xres, 4096, 1024, 4096);
}

// Round 4
// 736.465 us; speedup vs baseline: 1.2643x; 1.2643x over previous
//
#include <hip/hip_runtime.h>
#include <hip/hip_bf16.h>
#include <math.h>
#include <stdint.h>

typedef __bf16 bf16;
typedef __attribute__((ext_vector_type(8))) __bf16 bf16x8;
typedef __attribute__((ext_vector_type(4))) __bf16 bf16x4;
typedef __attribute__((ext_vector_type(4))) float f32x4;

static constexpr int cB = 2, cS = 2048, cCTX = 256, cD = 1024, cH = 16, cDH = 64, cDFF = 4096;

// async 16B global->LDS. HW semantics: dest = wave-uniform base + lane*16.
// Every call site MUST have lane i's lds ptr == base + 16*i bytes.
__device__ __forceinline__ void glds16(const bf16* g, bf16* l) {
  __builtin_amdgcn_global_load_lds(
      (const __attribute__((address_space(1))) void*)g,
      (__attribute__((address_space(3))) void*)l, 16, 0, 0);
}

// ---------------- transpose+convert: fp32 [K,N] -> bf16 [N,K], 64x64 tiles ----------------
__global__ __launch_bounds__(256) void k_transpose(const float* __restrict__ in,
                                                   bf16* __restrict__ out, int K, int N) {
  __shared__ bf16 tile[64][66];
  const int n0 = blockIdx.x * 64, k0 = blockIdx.y * 64;
  const int t = threadIdx.x;
  const int r = t >> 2, cb = (t & 3) * 16;
  const float* src = in + (size_t)(k0 + r) * N + n0 + cb;
#pragma unroll
  for (int q4 = 0; q4 < 4; ++q4) {
    f32x4 v = *(const f32x4*)(src + q4 * 4);
#pragma unroll
    for (int e = 0; e < 4; ++e) tile[r][cb + q4 * 4 + e] = (bf16)v[e];
  }
  __syncthreads();
  bf16* dst = out + (size_t)(n0 + r) * K + k0 + cb;
  bf16x8 o0, o1;
#pragma unroll
  for (int e = 0; e < 8; ++e) { o0[e] = tile[cb + e][r]; o1[e] = tile[cb + 8 + e][r]; }
  *(bf16x8*)(dst) = o0;
  *(bf16x8*)(dst + 8) = o1;
}

// ---------------- V transpose: rows [b*kvlen+s][vstride] cols h*64+d -> VT[(b*16+h)*64+d][kvlen] ----------------
__global__ __launch_bounds__(256) void k_vt(const bf16* __restrict__ V, int vstride,
                                            bf16* __restrict__ VT, int kvlen) {
  __shared__ bf16 tile[64][72];
  const int kt = blockIdx.x * 64, bh = blockIdx.y;
  const int b = bh >> 4, h = bh & 15;
  const int t = threadIdx.x, r = t >> 2, cb = (t & 3) * 16;
  const bf16* src = V + (size_t)(b * kvlen + kt + r) * vstride + h * 64 + cb;
  bf16x8 a0 = *(const bf16x8*)src;
  bf16x8 a1 = *(const bf16x8*)(src + 8);
#pragma unroll
  for (int e = 0; e < 8; ++e) { tile[r][cb + e] = a0[e]; tile[r][cb + 8 + e] = a1[e]; }
  __syncthreads();
  bf16* dst = VT + ((size_t)bh * 64 + r) * kvlen + kt + cb;
  bf16x8 o0, o1;
#pragma unroll
  for (int e = 0; e < 8; ++e) { o0[e] = tile[cb + e][r]; o1[e] = tile[cb + 8 + e][r]; }
  *(bf16x8*)(dst) = o0;
  *(bf16x8*)(dst + 8) = o1;
}

// ---------------- fp32 -> bf16 elementwise ----------------
__global__ __launch_bounds__(256) void k_f2b(const float* __restrict__ in, bf16* __restrict__ out) {
  const int base = (blockIdx.x * 256 + threadIdx.x) * 4;
  f32x4 v = *(const f32x4*)(in + base);
  bf16x4 o;
#pragma unroll
  for (int e = 0; e < 4; ++e) o[e] = (bf16)v[e];
  *(bf16x4*)(out + base) = o;
}

// ---------------- emb = t @ W + b  -> fp32 [2,2048] ----------------
__global__ __launch_bounds__(256) void k_emb(const float* __restrict__ t,
                                             const float* __restrict__ w,
                                             const float* __restrict__ bias,
                                             float* __restrict__ emb) {
  const int jj = threadIdx.x & 63;
  const int j = blockIdx.x * 64 + jj;
  const int kg = threadIdx.x >> 6;
  float a0 = 0.f, a1 = 0.f;
  for (int k = kg * 256; k < kg * 256 + 256; ++k) {
    float wv = w[(size_t)k * 2048 + j];
    a0 += t[k] * wv;
    a1 += t[1024 + k] * wv;
  }
  __shared__ float s0[4][64], s1[4][64];
  s0[kg][jj] = a0;
  s1[kg][jj] = a1;
  __syncthreads();
  if (threadIdx.x < 64) {
    emb[j] = s0[0][jj] + s0[1][jj] + s0[2][jj] + s0[3][jj] + bias[j];
    emb[2048 + j] = s1[0][jj] + s1[1][jj] + s1[2][jj] + s1[3][jj] + bias[j];
  }
}

// ---------------- AdaLN ----------------
__global__ __launch_bounds__(256) void k_adaln(const float* __restrict__ xres,
                                               const float* __restrict__ emb,
                                               bf16* __restrict__ h) {
  const int token = blockIdx.x;
  const int b = token >> 11;
  const float* x = xres + (size_t)token * 1024;
  const float* sc = emb + b * 2048;
  const int t = threadIdx.x;
  float v[4], s = 0.f, sq = 0.f;
#pragma unroll
  for (int i = 0; i < 4; ++i) {
    float u = x[t + 256 * i];
    v[i] = u; s += u; sq += u * u;
  }
#pragma unroll
  for (int off = 1; off < 64; off <<= 1) {
    s += __shfl_xor(s, off);
    sq += __shfl_xor(sq, off);
  }
  __shared__ float ss[4], ssq[4];
  const int wave = t >> 6;
  if ((t & 63) == 0) { ss[wave] = s; ssq[wave] = sq; }
  __syncthreads();
  const float S_ = ss[0] + ss[1] + ss[2] + ss[3];
  const float SQ = ssq[0] + ssq[1] + ssq[2] + ssq[3];
  const float mean = S_ * (1.f / 1024.f);
  const float var = SQ * (1.f / 1024.f) - mean * mean;
  const float rstd = rsqrtf(var + 1e-5f);
#pragma unroll
  for (int i = 0; i < 4; ++i) {
    const int c = t + 256 * i;
    float val = (v[i] - mean) * rstd * (1.f + sc[c]) + sc[1024 + c];
    h[(size_t)token * 1024 + c] = (bf16)val;
  }
}

// ---------------- GEMM: C[M,N] = A[M,K] @ Bt[N,K]^T (+bias)(+res). TN = 128 or 64. ----------------
template <int TN>
__global__ __launch_bounds__(256) void k_gemm_t(const bf16* __restrict__ A,
                                                const bf16* __restrict__ Bt,
                                                bf16* Cb, float* Cf,
                                                const float* __restrict__ bias,
                                                const float* res,
                                                int M, int N, int K) {
  constexpr int JN = TN / 32;
  __shared__ bf16 As[128 * 32];
  __shared__ bf16 Bs[TN * 32];
  const int m0 = blockIdx.y * 128, n0 = blockIdx.x * TN;
  const int tid = threadIdx.x;
  const int wave = tid >> 6, lane = tid & 63;
  const int quad = lane >> 4, l16 = lane & 15;
  const int mw = (wave >> 1) * 64, nw = (wave & 1) * (TN / 2);
  f32x4 acc[4][JN];
#pragma unroll
  for (int i = 0; i < 4; ++i)
#pragma unroll
    for (int j = 0; j < JN; ++j) acc[i][j] = (f32x4){0.f, 0.f, 0.f, 0.f};

  // lane-contiguity law: LDS byte off = r0*64 + c0*2 = tid*16  ✓
  const int r0 = tid >> 2, c0 = (tid & 3) << 3;
  const bf16* Ap = A + (size_t)(m0 + r0) * K + c0;
  const bf16* Bp = Bt + (size_t)(n0 + r0) * K + c0;
  bf16* lA = As + r0 * 32 + c0;
  bf16* lB = Bs + r0 * 32 + c0;

  for (int k0 = 0; k0 < K; k0 += 32) {
    __syncthreads();
    glds16(Ap + k0, lA);
    glds16(Ap + k0 + (size_t)64 * K, lA + 64 * 32);
    glds16(Bp + k0, lB);
    if (TN == 128) glds16(Bp + k0 + (size_t)64 * K, lB + 64 * 32);
    __syncthreads();
    bf16x8 af[4], bfr[JN];
#pragma unroll
    for (int i = 0; i < 4; ++i)
      af[i] = *(const bf16x8*)(As + (mw + i * 16 + l16) * 32 + quad * 8);
#pragma unroll
    for (int j = 0; j < JN; ++j)
      bfr[j] = *(const bf16x8*)(Bs + (nw + j * 16 + l16) * 32 + quad * 8);
#pragma unroll
    for (int i = 0; i < 4; ++i)
#pragma unroll
      for (int j = 0; j < JN; ++j)
        acc[i][j] = __builtin_amdgcn_mfma_f32_16x16x32_bf16(af[i], bfr[j], acc[i][j], 0, 0, 0);
  }

#pragma unroll
  for (int i = 0; i < 4; ++i) {
    const int rbase = m0 + mw + i * 16 + quad * 4;
#pragma unroll
    for (int j = 0; j < JN; ++j) {
      const int col = n0 + nw + j * 16 + l16;
      const float bv = bias ? bias[col] : 0.f;
#pragma unroll
      for (int r = 0; r < 4; ++r) {
        const size_t off = (size_t)(rbase + r) * N + col;
        float v2 = acc[i][j][r] + bv;
        if (res) v2 += res[off];
        if (Cf) Cf[off] = v2;
        if (Cb) Cb[off] = (bf16)v2;
      }
    }
  }
}

// ---------------- FF1 GEMM + fused GLU ----------------
__global__ __launch_bounds__(256) void k_gemm_glu(const bf16* __restrict__ A,
                                                  const bf16* __restrict__ Bt,
                                                  const float* __restrict__ bias,
                                                  bf16* __restrict__ Cb,
                                                  int M, int N, int K) {
  __shared__ bf16 As[128 * 32];
  __shared__ bf16 Ba[64 * 32];
  __shared__ bf16 Bg[64 * 32];
  const int m0 = blockIdx.y * 128, n0 = blockIdx.x * 64;
  const int tid = threadIdx.x;
  const int wave = tid >> 6, lane = tid & 63;
  const int quad = lane >> 4, l16 = lane & 15;
  const int mw = (wave >> 1) * 64, nw = (wave & 1) * 32;
  f32x4 aa[4][2], ag[4][2];
#pragma unroll
  for (int i = 0; i < 4; ++i)
#pragma unroll
    for (int j = 0; j < 2; ++j) {
      aa[i][j] = (f32x4){0.f, 0.f, 0.f, 0.f};
      ag[i][j] = (f32x4){0.f, 0.f, 0.f, 0.f};
    }

  const int r0 = tid >> 2, c0 = (tid & 3) << 3;
  const bf16* Ap = A + (size_t)(m0 + r0) * K + c0;
  const bf16* Bap = Bt + (size_t)(n0 + r0) * K + c0;
  const bf16* Bgp = Bt + (size_t)(N + n0 + r0) * K + c0;
  bf16* lA = As + r0 * 32 + c0;
  bf16* lBa = Ba + r0 * 32 + c0;
  bf16* lBg = Bg + r0 * 32 + c0;

  for (int k0 = 0; k0 < K; k0 += 32) {
    __syncthreads();
    glds16(Ap + k0, lA);
    glds16(Ap + k0 + (size_t)64 * K, lA + 64 * 32);
    glds16(Bap + k0, lBa);
    glds16(Bgp + k0, lBg);
    __syncthreads();
    bf16x8 af[4], ba[2], bg[2];
#pragma unroll
    for (int i = 0; i < 4; ++i)
      af[i] = *(const bf16x8*)(As + (mw + i * 16 + l16) * 32 + quad * 8);
#pragma unroll
    for (int j = 0; j < 2; ++j) {
      ba[j] = *(const bf16x8*)(Ba + (nw + j * 16 + l16) * 32 + quad * 8);
      bg[j] = *(const bf16x8*)(Bg + (nw + j * 16 + l16) * 32 + quad * 8);
    }
#pragma unroll
    for (int i = 0; i < 4; ++i)
#pragma unroll
      for (int j = 0; j < 2; ++j) {
        aa[i][j] = __builtin_amdgcn_mfma_f32_16x16x32_bf16(af[i], ba[j], aa[i][j], 0, 0, 0);
        ag[i][j] = __builtin_amdgcn_mfma_f32_16x16x32_bf16(af[i], bg[j], ag[i][j], 0, 0, 0);
      }
  }

#pragma unroll
  for (int i = 0; i < 4; ++i) {
    const int rbase = m0 + mw + i * 16 + quad * 4;
#pragma unroll
    for (int j = 0; j < 2; ++j) {
      const int col = n0 + nw + j * 16 + l16;
      const float ba_v = bias[col];
      const float bg_v = bias[N + col];
#pragma unroll
      for (int r = 0; r < 4; ++r) {
        float av = aa[i][j][r] + ba_v;
        float gv = ag[i][j][r] + bg_v;
        float ge = 0.5f * gv * (1.0f + erff(gv * 0.70710678118654752f));
        Cb[(size_t)(rbase + r) * N + col] = (bf16)(av * ge);
      }
    }
  }
}

// ---------------- flash attention, fixed-max softmax ----------------
// Q rows b*S+s stride qstride; K rows b*kvlen+s stride kstride; VT [(b*16+h)*64+d][kvlen].
__global__ __launch_bounds__(256) void k_attn(const bf16* __restrict__ Qp, int qstride,
                                              const bf16* __restrict__ Kp, int kstride,
                                              const bf16* __restrict__ VTp,
                                              bf16* __restrict__ Op, int kvlen) {
  const int qt = blockIdx.x * 64;
  const int hd = blockIdx.y;
  const int b = blockIdx.z;
  const int tid = threadIdx.x;
  const int wave = tid >> 6, lane = tid & 63;
  const int quad = lane >> 4, l16 = lane & 15;

  __shared__ __align__(16) bf16 Ks[64 * 64];        // [key][d]
  __shared__ __align__(16) bf16 Vs[64 * 64];        // [d][key]
  __shared__ __align__(16) bf16 Ps[4][16 * 72];     // per-wave P, stride 72

  // Q A-frags, 1/8 folded in
  const bf16* qrow = Qp + (size_t)(b * cS + qt + wave * 16 + l16) * qstride + hd * 64;
  bf16x8 qf[2];
#pragma unroll
  for (int c = 0; c < 2; ++c) {
    bf16x8 raw = *(const bf16x8*)(qrow + c * 32 + quad * 8);
#pragma unroll
    for (int e = 0; e < 8; ++e) qf[c][e] = (bf16)((float)raw[e] * 0.125f);
  }

  float l_part[4] = {0.f, 0.f, 0.f, 0.f};
  f32x4 o_acc[4];
#pragma unroll
  for (int n = 0; n < 4; ++n) o_acc[n] = (f32x4){0.f, 0.f, 0.f, 0.f};

  // glds16 staging: wave w stages rows 16w..16w+15 of the 64x64 (128B/row) tile.
  // lane i -> row 16w + (i>>3), col elems (i&7)*8; LDS byte = 2048w + 16i  ✓ law
  const int lrow = wave * 16 + (lane >> 3);
  const int lcol = (lane & 7) * 8;
  const bf16* kbase = Kp + (size_t)(b * kvlen + lrow) * kstride + hd * 64 + lcol;
  const bf16* vbase = VTp + ((size_t)((b * 16 + hd) * 64 + lrow)) * kvlen + lcol;
  bf16* lk = Ks + lrow * 64 + lcol;
  bf16* lv = Vs + lrow * 64 + lcol;

  for (int kt = 0; kt < kvlen; kt += 64) {
    __syncthreads();
    const bf16* kg = kbase + (size_t)kt * kstride;
    glds16(kg, lk);
    glds16(kg + (size_t)8 * kstride, lk + 8 * 64);       // rows +8
    glds16(vbase + kt, lv);
    glds16(vbase + kt + (size_t)8 * kvlen, lv + 8 * 64); // d-rows +8
    __syncthreads();

    // scores
    f32x4 s[4];
#pragma unroll
    for (int t = 0; t < 4; ++t) {
      f32x4 accs = (f32x4){0.f, 0.f, 0.f, 0.f};
#pragma unroll
      for (int c = 0; c < 2; ++c) {
        bf16x8 kf = *(const bf16x8*)(Ks + (t * 16 + l16) * 64 + c * 32 + quad * 8);
        accs = __builtin_amdgcn_mfma_f32_16x16x32_bf16(qf[c], kf, accs, 0, 0, 0);
      }
      s[t] = accs;
    }

    // fixed-max softmax: p = exp(s); per-lane partial sums only
#pragma unroll
    for (int t = 0; t < 4; ++t)
#pragma unroll
      for (int r = 0; r < 4; ++r) {
        float p = __expf(s[t][r]);
        Ps[wave][(quad * 4 + r) * 72 + t * 16 + l16] = (bf16)p;
        l_part[r] += p;
      }

    // PV
    bf16x8 pf[2];
#pragma unroll
    for (int c = 0; c < 2; ++c)
      pf[c] = *(const bf16x8*)(&Ps[wave][l16 * 72 + c * 32 + quad * 8]);
#pragma unroll
    for (int n = 0; n < 4; ++n)
#pragma unroll
      for (int c = 0; c < 2; ++c) {
        bf16x8 vf = *(const bf16x8*)(Vs + (n * 16 + l16) * 64 + c * 32 + quad * 8);
        o_acc[n] = __builtin_amdgcn_mfma_f32_16x16x32_bf16(pf[c], vf, o_acc[n], 0, 0, 0);
      }
  }

  float rl[4];
#pragma unroll
  for (int r = 0; r < 4; ++r) {
    float v = l_part[r];
    v += __shfl_xor(v, 1);
    v += __shfl_xor(v, 2);
    v += __shfl_xor(v, 4);
    v += __shfl_xor(v, 8);
    rl[r] = 1.f / v;
  }
#pragma unroll
  for (int n = 0; n < 4; ++n)
#pragma unroll
    for (int r = 0; r < 4; ++r) {
      const int srow = qt + wave * 16 + quad * 4 + r;
      const int d = n * 16 + l16;
      Op[(size_t)(b * cS + srow) * 1024 + hd * 64 + d] = (bf16)(o_acc[n][r] * rl[r]);
    }
}

// ---------------- launch ----------------
extern "C" void kernel_launch(void* const* d_in, const int* in_sizes, int n_in,
                              void* d_out, int out_size, void* d_ws, size_t ws_size,
                              hipStream_t stream) {
  const float* x    = (const float*)d_in[0];
  const float* tt   = (const float*)d_in[1];
  const float* ctx  = (const float*)d_in[2];
  const float* a1wq = (const float*)d_in[3];
  const float* a1wk = (const float*)d_in[4];
  const float* a1wv = (const float*)d_in[5];
  const float* a1wo = (const float*)d_in[6];
  const float* a1bo = (const float*)d_in[7];
  const float* a2wq = (const float*)d_in[8];
  const float* a2wk = (const float*)d_in[9];
  const float* a2wv = (const float*)d_in[10];
  const float* a2wo = (const float*)d_in[11];
  const float* a2bo = (const float*)d_in[12];
  const float* fw1  = (const float*)d_in[13];
  const float* fb1  = (const float*)d_in[14];
  const float* fw2  = (const float*)d_in[15];
  const float* fb2  = (const float*)d_in[16];
  const float* n1w  = (const float*)d_in[17];
  const float* n1b  = (const float*)d_in[18];
  const float* n2w  = (const float*)d_in[19];
  const float* n2b  = (const float*)d_in[20];
  const float* n3w  = (const float*)d_in[21];
  const float* n3b  = (const float*)d_in[22];

  char* ws = (char*)d_ws;
  const size_t MB = 1ull << 20;
  bf16* wqkv1 = (bf16*)(ws + 0 * MB);              // [3072,1024], 6 MB
  bf16* wto1  = (bf16*)(ws + 6 * MB);
  bf16* wtq2  = (bf16*)(ws + 8 * MB);
  bf16* wkv2w = (bf16*)(ws + 10 * MB);             // [2048,1024], 4 MB
  bf16* wto2  = (bf16*)(ws + 14 * MB);
  bf16* wtf1  = (bf16*)(ws + 16 * MB);             // [8192,1024], 16 MB
  bf16* wtf2  = (bf16*)(ws + 32 * MB);             // [1024,4096], 8 MB
  float* emb1 = (float*)(ws + 40 * MB);
  float* emb2 = (float*)(ws + 40 * MB + 65536);
  float* emb3 = (float*)(ws + 40 * MB + 131072);
  bf16* ctxb  = (bf16*)(ws + 40 * MB + 262144);    // [512,1024], 1 MB
  float* xres = (float*)(ws + 42 * MB);            // fp32 residual, 16 MB
  bf16* h     = (bf16*)(ws + 58 * MB);             // 8 MB
  bf16* ao    = h;                                 // attn-out aliases h
  bf16* qkv   = (bf16*)(ws + 66 * MB);             // [4096,3072], 24 MB
  bf16* q2    = qkv;
  bf16* vT1   = (bf16*)(ws + 90 * MB);             // [32*64,2048], 8 MB
  bf16* kv2   = (bf16*)(ws + 0 * MB);              // [512,2048], 2 MB (aliases dead wqkv1)
  bf16* vT2   = (bf16*)(ws + 2 * MB);              // [32*64,256], 1 MB
  bf16* g     = (bf16*)(ws + 66 * MB);             // [4096,4096], 32 MB (aliases qkv+vT1)
  float* out  = (float*)d_out;

  const dim3 blk(256);

  k_transpose<<<dim3(16, 16), blk, 0, stream>>>(a1wq, wqkv1, 1024, 1024);
  k_transpose<<<dim3(16, 16), blk, 0, stream>>>(a1wk, wqkv1 + 1024 * 1024, 1024, 1024);
  k_transpose<<<dim3(16, 16), blk, 0, stream>>>(a1wv, wqkv1 + 2 * 1024 * 1024, 1024, 1024);
  k_transpose<<<dim3(16, 16), blk, 0, stream>>>(a1wo, wto1, 1024, 1024);
  k_transpose<<<dim3(16, 16), blk, 0, stream>>>(a2wq, wtq2, 1024, 1024);
  k_transpose<<<dim3(16, 16), blk, 0, stream>>>(a2wk, wkv2w, 1024, 1024);
  k_transpose<<<dim3(16, 16), blk, 0, stream>>>(a2wv, wkv2w + 1024 * 1024, 1024, 1024);
  k_transpose<<<dim3(16, 16), blk, 0, stream>>>(a2wo, wto2, 1024, 1024);
  k_transpose<<<dim3(128, 16), blk, 0, stream>>>(fw1, wtf1, 1024, 8192);
  k_transpose<<<dim3(16, 64), blk, 0, stream>>>(fw2, wtf2, 4096, 1024);

  k_emb<<<32, blk, 0, stream>>>(tt, n1w, n1b, emb1);
  k_emb<<<32, blk, 0, stream>>>(tt, n2w, n2b, emb2);
  k_emb<<<32, blk, 0, stream>>>(tt, n3w, n3b, emb3);
  k_f2b<<<512, blk, 0, stream>>>(ctx, ctxb);

  // ---- block 1: self-attention ----
  k_adaln<<<4096, blk, 0, stream>>>(x, emb1, h);
  k_gemm_t<128><<<dim3(24, 32), blk, 0, stream>>>(h, wqkv1, qkv, nullptr, nullptr, nullptr, 4096, 3072, 1024);
  k_vt<<<dim3(32, 32), blk, 0, stream>>>(qkv + 2048, 3072, vT1, 2048);
  k_attn<<<dim3(32, 16, 2), blk, 0, stream>>>(qkv, 3072, qkv + 1024, 3072, vT1, ao, 2048);
  k_gemm_t<64><<<dim3(16, 32), blk, 0, stream>>>(ao, wto1, nullptr, xres, a1bo, x, 4096, 1024, 1024);

  // ---- block 2: cross-attention ----
  k_adaln<<<4096, blk, 0, stream>>>(xres, emb2, h);
  k_gemm_t<64><<<dim3(16, 32), blk, 0, stream>>>(h, wtq2, q2, nullptr, nullptr, nullptr, 4096, 1024, 1024);
  k_gemm_t<128><<<dim3(16, 4), blk, 0, stream>>>(ctxb, wkv2w, kv2, nullptr, nullptr, nullptr, 512, 2048, 1024);
  k_vt<<<dim3(4, 32), blk, 0, stream>>>(kv2 + 1024, 2048, vT2, 256);
  k_attn<<<dim3(32, 16, 2), blk, 0, stream>>>(q2, 1024, kv2, 2048, vT2, ao, 256);
  k_gemm_t<64><<<dim3(16, 32), blk, 0, stream>>>(ao, wto2, nullptr, xres, a2bo, xres, 4096, 1024, 1024);

  // ---- block 3: gated-GELU FFN ----
  k_adaln<<<4096, blk, 0, stream>>>(xres, emb3, h);
  k_gemm_glu<<<dim3(64, 32), blk, 0, stream>>>(h, wtf1, fb1, g, 4096, 4096, 1024);
  k_gemm_t<64><<<dim3(16, 32), blk, 0, stream>>>(g, wtf2, nullptr, out, fb2, xres, 4096, 1024, 4096);
}

// Round 5
// 697.856 us; speedup vs baseline: 1.3342x; 1.0553x over previous
//
#include <hip/hip_runtime.h>
#include <hip/hip_bf16.h>
#include <math.h>
#include <stdint.h>

typedef __bf16 bf16;
typedef __attribute__((ext_vector_type(8))) __bf16 bf16x8;
typedef __attribute__((ext_vector_type(4))) __bf16 bf16x4;
typedef __attribute__((ext_vector_type(4))) float f32x4;

static constexpr int cB = 2, cS = 2048, cCTX = 256, cD = 1024, cH = 16, cDH = 64, cDFF = 4096;

// async 16B global->LDS. HW semantics: dest = wave-uniform base + lane*16.
// Every call site MUST have lane i's lds ptr == base + 16*i bytes.
__device__ __forceinline__ void glds16(const bf16* g, bf16* l) {
  __builtin_amdgcn_global_load_lds(
      (const __attribute__((address_space(1))) void*)g,
      (__attribute__((address_space(3))) void*)l, 16, 0, 0);
}

// ---------------- transpose+convert: fp32 [K,N] -> bf16 [N,K], 64x64 tiles ----------------
__global__ __launch_bounds__(256) void k_transpose(const float* __restrict__ in,
                                                   bf16* __restrict__ out, int K, int N) {
  __shared__ bf16 tile[64][66];
  const int n0 = blockIdx.x * 64, k0 = blockIdx.y * 64;
  const int t = threadIdx.x;
  const int r = t >> 2, cb = (t & 3) * 16;
  const float* src = in + (size_t)(k0 + r) * N + n0 + cb;
#pragma unroll
  for (int q4 = 0; q4 < 4; ++q4) {
    f32x4 v = *(const f32x4*)(src + q4 * 4);
#pragma unroll
    for (int e = 0; e < 4; ++e) tile[r][cb + q4 * 4 + e] = (bf16)v[e];
  }
  __syncthreads();
  bf16* dst = out + (size_t)(n0 + r) * K + k0 + cb;
  bf16x8 o0, o1;
#pragma unroll
  for (int e = 0; e < 8; ++e) { o0[e] = tile[cb + e][r]; o1[e] = tile[cb + 8 + e][r]; }
  *(bf16x8*)(dst) = o0;
  *(bf16x8*)(dst + 8) = o1;
}

// ---------------- V transpose -> VT[(b*16+h)*64+d][kvlen] ----------------
__global__ __launch_bounds__(256) void k_vt(const bf16* __restrict__ V, int vstride,
                                            bf16* __restrict__ VT, int kvlen) {
  __shared__ bf16 tile[64][72];
  const int kt = blockIdx.x * 64, bh = blockIdx.y;
  const int b = bh >> 4, h = bh & 15;
  const int t = threadIdx.x, r = t >> 2, cb = (t & 3) * 16;
  const bf16* src = V + (size_t)(b * kvlen + kt + r) * vstride + h * 64 + cb;
  bf16x8 a0 = *(const bf16x8*)src;
  bf16x8 a1 = *(const bf16x8*)(src + 8);
#pragma unroll
  for (int e = 0; e < 8; ++e) { tile[r][cb + e] = a0[e]; tile[r][cb + 8 + e] = a1[e]; }
  __syncthreads();
  bf16* dst = VT + ((size_t)bh * 64 + r) * kvlen + kt + cb;
  bf16x8 o0, o1;
#pragma unroll
  for (int e = 0; e < 8; ++e) { o0[e] = tile[cb + e][r]; o1[e] = tile[cb + 8 + e][r]; }
  *(bf16x8*)(dst) = o0;
  *(bf16x8*)(dst + 8) = o1;
}

// ---------------- fp32 -> bf16 elementwise ----------------
__global__ __launch_bounds__(256) void k_f2b(const float* __restrict__ in, bf16* __restrict__ out) {
  const int base = (blockIdx.x * 256 + threadIdx.x) * 4;
  f32x4 v = *(const f32x4*)(in + base);
  bf16x4 o;
#pragma unroll
  for (int e = 0; e < 4; ++e) o[e] = (bf16)v[e];
  *(bf16x4*)(out + base) = o;
}

// ---------------- emb = t @ W + b  -> fp32 [2,2048] ----------------
__global__ __launch_bounds__(256) void k_emb(const float* __restrict__ t,
                                             const float* __restrict__ w,
                                             const float* __restrict__ bias,
                                             float* __restrict__ emb) {
  const int jj = threadIdx.x & 63;
  const int j = blockIdx.x * 64 + jj;
  const int kg = threadIdx.x >> 6;
  float a0 = 0.f, a1 = 0.f;
  for (int k = kg * 256; k < kg * 256 + 256; ++k) {
    float wv = w[(size_t)k * 2048 + j];
    a0 += t[k] * wv;
    a1 += t[1024 + k] * wv;
  }
  __shared__ float s0[4][64], s1[4][64];
  s0[kg][jj] = a0;
  s1[kg][jj] = a1;
  __syncthreads();
  if (threadIdx.x < 64) {
    emb[j] = s0[0][jj] + s0[1][jj] + s0[2][jj] + s0[3][jj] + bias[j];
    emb[2048 + j] = s1[0][jj] + s1[1][jj] + s1[2][jj] + s1[3][jj] + bias[j];
  }
}

// ---------------- AdaLN ----------------
__global__ __launch_bounds__(256) void k_adaln(const float* __restrict__ xres,
                                               const float* __restrict__ emb,
                                               bf16* __restrict__ h) {
  const int token = blockIdx.x;
  const int b = token >> 11;
  const float* x = xres + (size_t)token * 1024;
  const float* sc = emb + b * 2048;
  const int t = threadIdx.x;
  float v[4], s = 0.f, sq = 0.f;
#pragma unroll
  for (int i = 0; i < 4; ++i) {
    float u = x[t + 256 * i];
    v[i] = u; s += u; sq += u * u;
  }
#pragma unroll
  for (int off = 1; off < 64; off <<= 1) {
    s += __shfl_xor(s, off);
    sq += __shfl_xor(sq, off);
  }
  __shared__ float ss[4], ssq[4];
  const int wave = t >> 6;
  if ((t & 63) == 0) { ss[wave] = s; ssq[wave] = sq; }
  __syncthreads();
  const float S_ = ss[0] + ss[1] + ss[2] + ss[3];
  const float SQ = ssq[0] + ssq[1] + ssq[2] + ssq[3];
  const float mean = S_ * (1.f / 1024.f);
  const float var = SQ * (1.f / 1024.f) - mean * mean;
  const float rstd = rsqrtf(var + 1e-5f);
#pragma unroll
  for (int i = 0; i < 4; ++i) {
    const int c = t + 256 * i;
    float val = (v[i] - mean) * rstd * (1.f + sc[c]) + sc[1024 + c];
    h[(size_t)token * 1024 + c] = (bf16)val;
  }
}

// ---------------- GEMM: C[M,N] = A[M,K] @ Bt[N,K]^T (+bias)(+res). BK=64, 2x32 panels ----------------
// LDS panels keep the verified m97 stride-32 geometry; 2 K-halves per barrier pair.
template <int TN>
__global__ __launch_bounds__(256) void k_gemm_t(const bf16* __restrict__ A,
                                                const bf16* __restrict__ Bt,
                                                bf16* Cb, float* Cf,
                                                const float* __restrict__ bias,
                                                const float* res,
                                                int M, int N, int K) {
  constexpr int JN = TN / 32;
  __shared__ bf16 As[2 * 128 * 32];   // [panel][row][32]
  __shared__ bf16 Bs[2 * TN * 32];
  const int m0 = blockIdx.y * 128, n0 = blockIdx.x * TN;
  const int tid = threadIdx.x;
  const int wave = tid >> 6, lane = tid & 63;
  const int quad = lane >> 4, l16 = lane & 15;
  const int mw = (wave >> 1) * 64, nw = (wave & 1) * (TN / 2);
  f32x4 acc[4][JN];
#pragma unroll
  for (int i = 0; i < 4; ++i)
#pragma unroll
    for (int j = 0; j < JN; ++j) acc[i][j] = (f32x4){0.f, 0.f, 0.f, 0.f};

  // lane-contiguity law per panel: LDS byte off = r0*64 + c0*2 = tid*16  ✓
  const int r0 = tid >> 2, c0 = (tid & 3) << 3;
  const bf16* Ap = A + (size_t)(m0 + r0) * K + c0;
  const bf16* Bp = Bt + (size_t)(n0 + r0) * K + c0;
  bf16* lA = As + r0 * 32 + c0;
  bf16* lB = Bs + r0 * 32 + c0;

  for (int k0 = 0; k0 < K; k0 += 64) {
    __syncthreads();
    // A: 128 rows x 64 cols as two 32-col panels
    glds16(Ap + k0, lA);
    glds16(Ap + k0 + (size_t)64 * K, lA + 64 * 32);
    glds16(Ap + k0 + 32, lA + 128 * 32);
    glds16(Ap + k0 + 32 + (size_t)64 * K, lA + 192 * 32);
    // B: TN rows x 64 cols as two panels
    glds16(Bp + k0, lB);
    if (TN == 128) glds16(Bp + k0 + (size_t)64 * K, lB + 64 * 32);
    glds16(Bp + k0 + 32, lB + TN * 32);
    if (TN == 128) glds16(Bp + k0 + 32 + (size_t)64 * K, lB + TN * 32 + 64 * 32);
    __syncthreads();
#pragma unroll
    for (int kh = 0; kh < 2; ++kh) {
      const bf16* Asp = As + kh * 128 * 32;
      const bf16* Bsp = Bs + kh * TN * 32;
      bf16x8 af[4], bfr[JN];
#pragma unroll
      for (int i = 0; i < 4; ++i)
        af[i] = *(const bf16x8*)(Asp + (mw + i * 16 + l16) * 32 + quad * 8);
#pragma unroll
      for (int j = 0; j < JN; ++j)
        bfr[j] = *(const bf16x8*)(Bsp + (nw + j * 16 + l16) * 32 + quad * 8);
#pragma unroll
      for (int i = 0; i < 4; ++i)
#pragma unroll
        for (int j = 0; j < JN; ++j)
          acc[i][j] = __builtin_amdgcn_mfma_f32_16x16x32_bf16(af[i], bfr[j], acc[i][j], 0, 0, 0);
    }
  }

#pragma unroll
  for (int i = 0; i < 4; ++i) {
    const int rbase = m0 + mw + i * 16 + quad * 4;
#pragma unroll
    for (int j = 0; j < JN; ++j) {
      const int col = n0 + nw + j * 16 + l16;
      const float bv = bias ? bias[col] : 0.f;
#pragma unroll
      for (int r = 0; r < 4; ++r) {
        const size_t off = (size_t)(rbase + r) * N + col;
        float v2 = acc[i][j][r] + bv;
        if (res) v2 += res[off];
        if (Cf) Cf[off] = v2;
        if (Cb) Cb[off] = (bf16)v2;
      }
    }
  }
}

// ---------------- FF1 GEMM + fused GLU (BK=64 panels) ----------------
__global__ __launch_bounds__(256) void k_gemm_glu(const bf16* __restrict__ A,
                                                  const bf16* __restrict__ Bt,
                                                  const float* __restrict__ bias,
                                                  bf16* __restrict__ Cb,
                                                  int M, int N, int K) {
  __shared__ bf16 As[2 * 128 * 32];
  __shared__ bf16 Ba[2 * 64 * 32];
  __shared__ bf16 Bg[2 * 64 * 32];
  const int m0 = blockIdx.y * 128, n0 = blockIdx.x * 64;
  const int tid = threadIdx.x;
  const int wave = tid >> 6, lane = tid & 63;
  const int quad = lane >> 4, l16 = lane & 15;
  const int mw = (wave >> 1) * 64, nw = (wave & 1) * 32;
  f32x4 aa[4][2], ag[4][2];
#pragma unroll
  for (int i = 0; i < 4; ++i)
#pragma unroll
    for (int j = 0; j < 2; ++j) {
      aa[i][j] = (f32x4){0.f, 0.f, 0.f, 0.f};
      ag[i][j] = (f32x4){0.f, 0.f, 0.f, 0.f};
    }

  const int r0 = tid >> 2, c0 = (tid & 3) << 3;
  const bf16* Ap = A + (size_t)(m0 + r0) * K + c0;
  const bf16* Bap = Bt + (size_t)(n0 + r0) * K + c0;
  const bf16* Bgp = Bt + (size_t)(N + n0 + r0) * K + c0;
  bf16* lA = As + r0 * 32 + c0;
  bf16* lBa = Ba + r0 * 32 + c0;
  bf16* lBg = Bg + r0 * 32 + c0;

  for (int k0 = 0; k0 < K; k0 += 64) {
    __syncthreads();
    glds16(Ap + k0, lA);
    glds16(Ap + k0 + (size_t)64 * K, lA + 64 * 32);
    glds16(Ap + k0 + 32, lA + 128 * 32);
    glds16(Ap + k0 + 32 + (size_t)64 * K, lA + 192 * 32);
    glds16(Bap + k0, lBa);
    glds16(Bap + k0 + 32, lBa + 64 * 32);
    glds16(Bgp + k0, lBg);
    glds16(Bgp + k0 + 32, lBg + 64 * 32);
    __syncthreads();
#pragma unroll
    for (int kh = 0; kh < 2; ++kh) {
      const bf16* Asp = As + kh * 128 * 32;
      const bf16* Bap_s = Ba + kh * 64 * 32;
      const bf16* Bgp_s = Bg + kh * 64 * 32;
      bf16x8 af[4], ba[2], bg[2];
#pragma unroll
      for (int i = 0; i < 4; ++i)
        af[i] = *(const bf16x8*)(Asp + (mw + i * 16 + l16) * 32 + quad * 8);
#pragma unroll
      for (int j = 0; j < 2; ++j) {
        ba[j] = *(const bf16x8*)(Bap_s + (nw + j * 16 + l16) * 32 + quad * 8);
        bg[j] = *(const bf16x8*)(Bgp_s + (nw + j * 16 + l16) * 32 + quad * 8);
      }
#pragma unroll
      for (int i = 0; i < 4; ++i)
#pragma unroll
        for (int j = 0; j < 2; ++j) {
          aa[i][j] = __builtin_amdgcn_mfma_f32_16x16x32_bf16(af[i], ba[j], aa[i][j], 0, 0, 0);
          ag[i][j] = __builtin_amdgcn_mfma_f32_16x16x32_bf16(af[i], bg[j], ag[i][j], 0, 0, 0);
        }
    }
  }

#pragma unroll
  for (int i = 0; i < 4; ++i) {
    const int rbase = m0 + mw + i * 16 + quad * 4;
#pragma unroll
    for (int j = 0; j < 2; ++j) {
      const int col = n0 + nw + j * 16 + l16;
      const float ba_v = bias[col];
      const float bg_v = bias[N + col];
#pragma unroll
      for (int r = 0; r < 4; ++r) {
        float av = aa[i][j][r] + ba_v;
        float gv = ag[i][j][r] + bg_v;
        float ge = 0.5f * gv * (1.0f + erff(gv * 0.70710678118654752f));
        Cb[(size_t)(rbase + r) * N + col] = (bf16)(av * ge);
      }
    }
  }
}

// ---------------- flash attention, fixed-max softmax ----------------
__global__ __launch_bounds__(256) void k_attn(const bf16* __restrict__ Qp, int qstride,
                                              const bf16* __restrict__ Kp, int kstride,
                                              const bf16* __restrict__ VTp,
                                              bf16* __restrict__ Op, int kvlen) {
  const int qt = blockIdx.x * 64;
  const int hd = blockIdx.y;
  const int b = blockIdx.z;
  const int tid = threadIdx.x;
  const int wave = tid >> 6, lane = tid & 63;
  const int quad = lane >> 4, l16 = lane & 15;

  __shared__ __align__(16) bf16 Ks[64 * 64];
  __shared__ __align__(16) bf16 Vs[64 * 64];
  __shared__ __align__(16) bf16 Ps[4][16 * 72];

  const bf16* qrow = Qp + (size_t)(b * cS + qt + wave * 16 + l16) * qstride + hd * 64;
  bf16x8 qf[2];
#pragma unroll
  for (int c = 0; c < 2; ++c) {
    bf16x8 raw = *(const bf16x8*)(qrow + c * 32 + quad * 8);
#pragma unroll
    for (int e = 0; e < 8; ++e) qf[c][e] = (bf16)((float)raw[e] * 0.125f);
  }

  float l_part[4] = {0.f, 0.f, 0.f, 0.f};
  f32x4 o_acc[4];
#pragma unroll
  for (int n = 0; n < 4; ++n) o_acc[n] = (f32x4){0.f, 0.f, 0.f, 0.f};

  // lane i -> row 16w + (i>>3), col (i&7)*8; LDS byte = 2048w + 16i  ✓ law
  const int lrow = wave * 16 + (lane >> 3);
  const int lcol = (lane & 7) * 8;
  const bf16* kbase = Kp + (size_t)(b * kvlen + lrow) * kstride + hd * 64 + lcol;
  const bf16* vbase = VTp + ((size_t)((b * 16 + hd) * 64 + lrow)) * kvlen + lcol;
  bf16* lk = Ks + lrow * 64 + lcol;
  bf16* lv = Vs + lrow * 64 + lcol;

  for (int kt = 0; kt < kvlen; kt += 64) {
    __syncthreads();
    const bf16* kg = kbase + (size_t)kt * kstride;
    glds16(kg, lk);
    glds16(kg + (size_t)8 * kstride, lk + 8 * 64);
    glds16(vbase + kt, lv);
    glds16(vbase + kt + (size_t)8 * kvlen, lv + 8 * 64);
    __syncthreads();

    f32x4 s[4];
#pragma unroll
    for (int t = 0; t < 4; ++t) {
      f32x4 accs = (f32x4){0.f, 0.f, 0.f, 0.f};
#pragma unroll
      for (int c = 0; c < 2; ++c) {
        bf16x8 kf = *(const bf16x8*)(Ks + (t * 16 + l16) * 64 + c * 32 + quad * 8);
        accs = __builtin_amdgcn_mfma_f32_16x16x32_bf16(qf[c], kf, accs, 0, 0, 0);
      }
      s[t] = accs;
    }

#pragma unroll
    for (int t = 0; t < 4; ++t)
#pragma unroll
      for (int r = 0; r < 4; ++r) {
        float p = __expf(s[t][r]);
        Ps[wave][(quad * 4 + r) * 72 + t * 16 + l16] = (bf16)p;
        l_part[r] += p;
      }

    bf16x8 pf[2];
#pragma unroll
    for (int c = 0; c < 2; ++c)
      pf[c] = *(const bf16x8*)(&Ps[wave][l16 * 72 + c * 32 + quad * 8]);
#pragma unroll
    for (int n = 0; n < 4; ++n)
#pragma unroll
      for (int c = 0; c < 2; ++c) {
        bf16x8 vf = *(const bf16x8*)(Vs + (n * 16 + l16) * 64 + c * 32 + quad * 8);
        o_acc[n] = __builtin_amdgcn_mfma_f32_16x16x32_bf16(pf[c], vf, o_acc[n], 0, 0, 0);
      }
  }

  float rl[4];
#pragma unroll
  for (int r = 0; r < 4; ++r) {
    float v = l_part[r];
    v += __shfl_xor(v, 1);
    v += __shfl_xor(v, 2);
    v += __shfl_xor(v, 4);
    v += __shfl_xor(v, 8);
    rl[r] = 1.f / v;
  }
#pragma unroll
  for (int n = 0; n < 4; ++n)
#pragma unroll
    for (int r = 0; r < 4; ++r) {
      const int srow = qt + wave * 16 + quad * 4 + r;
      const int d = n * 16 + l16;
      Op[(size_t)(b * cS + srow) * 1024 + hd * 64 + d] = (bf16)(o_acc[n][r] * rl[r]);
    }
}

// ---------------- launch ----------------
extern "C" void kernel_launch(void* const* d_in, const int* in_sizes, int n_in,
                              void* d_out, int out_size, void* d_ws, size_t ws_size,
                              hipStream_t stream) {
  const float* x    = (const float*)d_in[0];
  const float* tt   = (const float*)d_in[1];
  const float* ctx  = (const float*)d_in[2];
  const float* a1wq = (const float*)d_in[3];
  const float* a1wk = (const float*)d_in[4];
  const float* a1wv = (const float*)d_in[5];
  const float* a1wo = (const float*)d_in[6];
  const float* a1bo = (const float*)d_in[7];
  const float* a2wq = (const float*)d_in[8];
  const float* a2wk = (const float*)d_in[9];
  const float* a2wv = (const float*)d_in[10];
  const float* a2wo = (const float*)d_in[11];
  const float* a2bo = (const float*)d_in[12];
  const float* fw1  = (const float*)d_in[13];
  const float* fb1  = (const float*)d_in[14];
  const float* fw2  = (const float*)d_in[15];
  const float* fb2  = (const float*)d_in[16];
  const float* n1w  = (const float*)d_in[17];
  const float* n1b  = (const float*)d_in[18];
  const float* n2w  = (const float*)d_in[19];
  const float* n2b  = (const float*)d_in[20];
  const float* n3w  = (const float*)d_in[21];
  const float* n3b  = (const float*)d_in[22];

  char* ws = (char*)d_ws;
  const size_t MB = 1ull << 20;
  bf16* wqkv1 = (bf16*)(ws + 0 * MB);              // [3072,1024], 6 MB
  bf16* wto1  = (bf16*)(ws + 6 * MB);
  bf16* wtq2  = (bf16*)(ws + 8 * MB);
  bf16* wkv2w = (bf16*)(ws + 10 * MB);             // [2048,1024], 4 MB
  bf16* wto2  = (bf16*)(ws + 14 * MB);
  bf16* wtf1  = (bf16*)(ws + 16 * MB);             // [8192,1024], 16 MB
  bf16* wtf2  = (bf16*)(ws + 32 * MB);             // [1024,4096], 8 MB
  float* emb1 = (float*)(ws + 40 * MB);
  float* emb2 = (float*)(ws + 40 * MB + 65536);
  float* emb3 = (float*)(ws + 40 * MB + 131072);
  bf16* ctxb  = (bf16*)(ws + 40 * MB + 262144);    // [512,1024], 1 MB
  float* xres = (float*)(ws + 42 * MB);            // fp32 residual, 16 MB
  bf16* h     = (bf16*)(ws + 58 * MB);             // 8 MB
  bf16* ao    = h;
  bf16* qkv   = (bf16*)(ws + 66 * MB);             // [4096,3072], 24 MB
  bf16* q2    = qkv;
  bf16* vT1   = (bf16*)(ws + 90 * MB);             // [32*64,2048], 8 MB
  bf16* kv2   = (bf16*)(ws + 0 * MB);              // [512,2048], 2 MB
  bf16* vT2   = (bf16*)(ws + 2 * MB);              // [32*64,256], 1 MB
  bf16* g     = (bf16*)(ws + 66 * MB);             // [4096,4096], 32 MB
  float* out  = (float*)d_out;

  const dim3 blk(256);

  k_transpose<<<dim3(16, 16), blk, 0, stream>>>(a1wq, wqkv1, 1024, 1024);
  k_transpose<<<dim3(16, 16), blk, 0, stream>>>(a1wk, wqkv1 + 1024 * 1024, 1024, 1024);
  k_transpose<<<dim3(16, 16), blk, 0, stream>>>(a1wv, wqkv1 + 2 * 1024 * 1024, 1024, 1024);
  k_transpose<<<dim3(16, 16), blk, 0, stream>>>(a1wo, wto1, 1024, 1024);
  k_transpose<<<dim3(16, 16), blk, 0, stream>>>(a2wq, wtq2, 1024, 1024);
  k_transpose<<<dim3(16, 16), blk, 0, stream>>>(a2wk, wkv2w, 1024, 1024);
  k_transpose<<<dim3(16, 16), blk, 0, stream>>>(a2wv, wkv2w + 1024 * 1024, 1024, 1024);
  k_transpose<<<dim3(16, 16), blk, 0, stream>>>(a2wo, wto2, 1024, 1024);
  k_transpose<<<dim3(128, 16), blk, 0, stream>>>(fw1, wtf1, 1024, 8192);
  k_transpose<<<dim3(16, 64), blk, 0, stream>>>(fw2, wtf2, 4096, 1024);

  k_emb<<<32, blk, 0, stream>>>(tt, n1w, n1b, emb1);
  k_emb<<<32, blk, 0, stream>>>(tt, n2w, n2b, emb2);
  k_emb<<<32, blk, 0, stream>>>(tt, n3w, n3b, emb3);
  k_f2b<<<512, blk, 0, stream>>>(ctx, ctxb);

  // ---- block 1: self-attention ----
  k_adaln<<<4096, blk, 0, stream>>>(x, emb1, h);
  k_gemm_t<128><<<dim3(24, 32), blk, 0, stream>>>(h, wqkv1, qkv, nullptr, nullptr, nullptr, 4096, 3072, 1024);
  k_vt<<<dim3(32, 32), blk, 0, stream>>>(qkv + 2048, 3072, vT1, 2048);
  k_attn<<<dim3(32, 16, 2), blk, 0, stream>>>(qkv, 3072, qkv + 1024, 3072, vT1, ao, 2048);
  k_gemm_t<64><<<dim3(16, 32), blk, 0, stream>>>(ao, wto1, nullptr, xres, a1bo, x, 4096, 1024, 1024);

  // ---- block 2: cross-attention ----
  k_adaln<<<4096, blk, 0, stream>>>(xres, emb2, h);
  k_gemm_t<64><<<dim3(16, 32), blk, 0, stream>>>(h, wtq2, q2, nullptr, nullptr, nullptr, 4096, 1024, 1024);
  k_gemm_t<128><<<dim3(16, 4), blk, 0, stream>>>(ctxb, wkv2w, kv2, nullptr, nullptr, nullptr, 512, 2048, 1024);
  k_vt<<<dim3(4, 32), blk, 0, stream>>>(kv2 + 1024, 2048, vT2, 256);
  k_attn<<<dim3(32, 16, 2), blk, 0, stream>>>(q2, 1024, kv2, 2048, vT2, ao, 256);
  k_gemm_t<64><<<dim3(16, 32), blk, 0, stream>>>(ao, wto2, nullptr, xres, a2bo, xres, 4096, 1024, 1024);

  // ---- block 3: gated-GELU FFN ----
  k_adaln<<<4096, blk, 0, stream>>>(xres, emb3, h);
  k_gemm_glu<<<dim3(64, 32), blk, 0, stream>>>(h, wtf1, fb1, g, 4096, 4096, 1024);
  k_gemm_t<64><<<dim3(16, 32), blk, 0, stream>>>(g, wtf2, nullptr, out, fb2, xres, 4096, 1024, 4096);
}

// Round 6
// 678.774 us; speedup vs baseline: 1.3717x; 1.0281x over previous
//
#include <hip/hip_runtime.h>
#include <hip/hip_bf16.h>
#include <math.h>
#include <stdint.h>

typedef __bf16 bf16;
typedef __attribute__((ext_vector_type(8))) __bf16 bf16x8;
typedef __attribute__((ext_vector_type(4))) __bf16 bf16x4;
typedef __attribute__((ext_vector_type(4))) float f32x4;

static constexpr int cB = 2, cS = 2048, cCTX = 256, cD = 1024, cH = 16, cDH = 64, cDFF = 4096;

// async 16B global->LDS. HW semantics: dest = wave-uniform base + lane*16.
// Every call site MUST have lane i's lds ptr == base + 16*i bytes.
__device__ __forceinline__ void glds16(const bf16* g, bf16* l) {
  __builtin_amdgcn_global_load_lds(
      (const __attribute__((address_space(1))) void*)g,
      (__attribute__((address_space(3))) void*)l, 16, 0, 0);
}

// ---------------- transpose+convert: fp32 [K,N] -> bf16 [N,K], 64x64 tiles ----------------
__global__ __launch_bounds__(256) void k_transpose(const float* __restrict__ in,
                                                   bf16* __restrict__ out, int K, int N) {
  __shared__ bf16 tile[64][66];
  const int n0 = blockIdx.x * 64, k0 = blockIdx.y * 64;
  const int t = threadIdx.x;
  const int r = t >> 2, cb = (t & 3) * 16;
  const float* src = in + (size_t)(k0 + r) * N + n0 + cb;
#pragma unroll
  for (int q4 = 0; q4 < 4; ++q4) {
    f32x4 v = *(const f32x4*)(src + q4 * 4);
#pragma unroll
    for (int e = 0; e < 4; ++e) tile[r][cb + q4 * 4 + e] = (bf16)v[e];
  }
  __syncthreads();
  bf16* dst = out + (size_t)(n0 + r) * K + k0 + cb;
  bf16x8 o0, o1;
#pragma unroll
  for (int e = 0; e < 8; ++e) { o0[e] = tile[cb + e][r]; o1[e] = tile[cb + 8 + e][r]; }
  *(bf16x8*)(dst) = o0;
  *(bf16x8*)(dst + 8) = o1;
}

// ---------------- V transpose -> VT[(b*16+h)*64+d][kvlen] ----------------
__global__ __launch_bounds__(256) void k_vt(const bf16* __restrict__ V, int vstride,
                                            bf16* __restrict__ VT, int kvlen) {
  __shared__ bf16 tile[64][72];
  const int kt = blockIdx.x * 64, bh = blockIdx.y;
  const int b = bh >> 4, h = bh & 15;
  const int t = threadIdx.x, r = t >> 2, cb = (t & 3) * 16;
  const bf16* src = V + (size_t)(b * kvlen + kt + r) * vstride + h * 64 + cb;
  bf16x8 a0 = *(const bf16x8*)src;
  bf16x8 a1 = *(const bf16x8*)(src + 8);
#pragma unroll
  for (int e = 0; e < 8; ++e) { tile[r][cb + e] = a0[e]; tile[r][cb + 8 + e] = a1[e]; }
  __syncthreads();
  bf16* dst = VT + ((size_t)bh * 64 + r) * kvlen + kt + cb;
  bf16x8 o0, o1;
#pragma unroll
  for (int e = 0; e < 8; ++e) { o0[e] = tile[cb + e][r]; o1[e] = tile[cb + 8 + e][r]; }
  *(bf16x8*)(dst) = o0;
  *(bf16x8*)(dst + 8) = o1;
}

// ---------------- fp32 -> bf16 elementwise ----------------
__global__ __launch_bounds__(256) void k_f2b(const float* __restrict__ in, bf16* __restrict__ out) {
  const int base = (blockIdx.x * 256 + threadIdx.x) * 4;
  f32x4 v = *(const f32x4*)(in + base);
  bf16x4 o;
#pragma unroll
  for (int e = 0; e < 4; ++e) o[e] = (bf16)v[e];
  *(bf16x4*)(out + base) = o;
}

// ---------------- emb = t @ W + b  -> fp32 [2,2048] ----------------
__global__ __launch_bounds__(256) void k_emb(const float* __restrict__ t,
                                             const float* __restrict__ w,
                                             const float* __restrict__ bias,
                                             float* __restrict__ emb) {
  const int jj = threadIdx.x & 63;
  const int j = blockIdx.x * 64 + jj;
  const int kg = threadIdx.x >> 6;
  float a0 = 0.f, a1 = 0.f;
  for (int k = kg * 256; k < kg * 256 + 256; ++k) {
    float wv = w[(size_t)k * 2048 + j];
    a0 += t[k] * wv;
    a1 += t[1024 + k] * wv;
  }
  __shared__ float s0[4][64], s1[4][64];
  s0[kg][jj] = a0;
  s1[kg][jj] = a1;
  __syncthreads();
  if (threadIdx.x < 64) {
    emb[j] = s0[0][jj] + s0[1][jj] + s0[2][jj] + s0[3][jj] + bias[j];
    emb[2048 + j] = s1[0][jj] + s1[1][jj] + s1[2][jj] + s1[3][jj] + bias[j];
  }
}

// ---------------- AdaLN ----------------
__global__ __launch_bounds__(256) void k_adaln(const float* __restrict__ xres,
                                               const float* __restrict__ emb,
                                               bf16* __restrict__ h) {
  const int token = blockIdx.x;
  const int b = token >> 11;
  const float* x = xres + (size_t)token * 1024;
  const float* sc = emb + b * 2048;
  const int t = threadIdx.x;
  float v[4], s = 0.f, sq = 0.f;
#pragma unroll
  for (int i = 0; i < 4; ++i) {
    float u = x[t + 256 * i];
    v[i] = u; s += u; sq += u * u;
  }
#pragma unroll
  for (int off = 1; off < 64; off <<= 1) {
    s += __shfl_xor(s, off);
    sq += __shfl_xor(sq, off);
  }
  __shared__ float ss[4], ssq[4];
  const int wave = t >> 6;
  if ((t & 63) == 0) { ss[wave] = s; ssq[wave] = sq; }
  __syncthreads();
  const float S_ = ss[0] + ss[1] + ss[2] + ss[3];
  const float SQ = ssq[0] + ssq[1] + ssq[2] + ssq[3];
  const float mean = S_ * (1.f / 1024.f);
  const float var = SQ * (1.f / 1024.f) - mean * mean;
  const float rstd = rsqrtf(var + 1e-5f);
#pragma unroll
  for (int i = 0; i < 4; ++i) {
    const int c = t + 256 * i;
    float val = (v[i] - mean) * rstd * (1.f + sc[c]) + sc[1024 + c];
    h[(size_t)token * 1024 + c] = (bf16)val;
  }
}

// ---------------- GEMM: C[M,N] = A[M,K] @ Bt[N,K]^T (+bias)(+res). BK=64, 2x32 panels ----------------
template <int TN>
__global__ __launch_bounds__(256) void k_gemm_t(const bf16* __restrict__ A,
                                                const bf16* __restrict__ Bt,
                                                bf16* Cb, float* Cf,
                                                const float* __restrict__ bias,
                                                const float* res,
                                                int M, int N, int K) {
  constexpr int JN = TN / 32;
  __shared__ bf16 As[2 * 128 * 32];
  __shared__ bf16 Bs[2 * TN * 32];
  const int m0 = blockIdx.y * 128, n0 = blockIdx.x * TN;
  const int tid = threadIdx.x;
  const int wave = tid >> 6, lane = tid & 63;
  const int quad = lane >> 4, l16 = lane & 15;
  const int mw = (wave >> 1) * 64, nw = (wave & 1) * (TN / 2);
  f32x4 acc[4][JN];
#pragma unroll
  for (int i = 0; i < 4; ++i)
#pragma unroll
    for (int j = 0; j < JN; ++j) acc[i][j] = (f32x4){0.f, 0.f, 0.f, 0.f};

  const int r0 = tid >> 2, c0 = (tid & 3) << 3;
  const bf16* Ap = A + (size_t)(m0 + r0) * K + c0;
  const bf16* Bp = Bt + (size_t)(n0 + r0) * K + c0;
  bf16* lA = As + r0 * 32 + c0;
  bf16* lB = Bs + r0 * 32 + c0;

  for (int k0 = 0; k0 < K; k0 += 64) {
    __syncthreads();
    glds16(Ap + k0, lA);
    glds16(Ap + k0 + (size_t)64 * K, lA + 64 * 32);
    glds16(Ap + k0 + 32, lA + 128 * 32);
    glds16(Ap + k0 + 32 + (size_t)64 * K, lA + 192 * 32);
    glds16(Bp + k0, lB);
    if (TN == 128) glds16(Bp + k0 + (size_t)64 * K, lB + 64 * 32);
    glds16(Bp + k0 + 32, lB + TN * 32);
    if (TN == 128) glds16(Bp + k0 + 32 + (size_t)64 * K, lB + TN * 32 + 64 * 32);
    __syncthreads();
#pragma unroll
    for (int kh = 0; kh < 2; ++kh) {
      const bf16* Asp = As + kh * 128 * 32;
      const bf16* Bsp = Bs + kh * TN * 32;
      bf16x8 af[4], bfr[JN];
#pragma unroll
      for (int i = 0; i < 4; ++i)
        af[i] = *(const bf16x8*)(Asp + (mw + i * 16 + l16) * 32 + quad * 8);
#pragma unroll
      for (int j = 0; j < JN; ++j)
        bfr[j] = *(const bf16x8*)(Bsp + (nw + j * 16 + l16) * 32 + quad * 8);
#pragma unroll
      for (int i = 0; i < 4; ++i)
#pragma unroll
        for (int j = 0; j < JN; ++j)
          acc[i][j] = __builtin_amdgcn_mfma_f32_16x16x32_bf16(af[i], bfr[j], acc[i][j], 0, 0, 0);
    }
  }

#pragma unroll
  for (int i = 0; i < 4; ++i) {
    const int rbase = m0 + mw + i * 16 + quad * 4;
#pragma unroll
    for (int j = 0; j < JN; ++j) {
      const int col = n0 + nw + j * 16 + l16;
      const float bv = bias ? bias[col] : 0.f;
#pragma unroll
      for (int r = 0; r < 4; ++r) {
        const size_t off = (size_t)(rbase + r) * N + col;
        float v2 = acc[i][j][r] + bv;
        if (res) v2 += res[off];
        if (Cf) Cf[off] = v2;
        if (Cb) Cb[off] = (bf16)v2;
      }
    }
  }
}

// ---------------- FF1 GEMM + fused GLU (BK=64 panels) ----------------
__global__ __launch_bounds__(256) void k_gemm_glu(const bf16* __restrict__ A,
                                                  const bf16* __restrict__ Bt,
                                                  const float* __restrict__ bias,
                                                  bf16* __restrict__ Cb,
                                                  int M, int N, int K) {
  __shared__ bf16 As[2 * 128 * 32];
  __shared__ bf16 Ba[2 * 64 * 32];
  __shared__ bf16 Bg[2 * 64 * 32];
  const int m0 = blockIdx.y * 128, n0 = blockIdx.x * 64;
  const int tid = threadIdx.x;
  const int wave = tid >> 6, lane = tid & 63;
  const int quad = lane >> 4, l16 = lane & 15;
  const int mw = (wave >> 1) * 64, nw = (wave & 1) * 32;
  f32x4 aa[4][2], ag[4][2];
#pragma unroll
  for (int i = 0; i < 4; ++i)
#pragma unroll
    for (int j = 0; j < 2; ++j) {
      aa[i][j] = (f32x4){0.f, 0.f, 0.f, 0.f};
      ag[i][j] = (f32x4){0.f, 0.f, 0.f, 0.f};
    }

  const int r0 = tid >> 2, c0 = (tid & 3) << 3;
  const bf16* Ap = A + (size_t)(m0 + r0) * K + c0;
  const bf16* Bap = Bt + (size_t)(n0 + r0) * K + c0;
  const bf16* Bgp = Bt + (size_t)(N + n0 + r0) * K + c0;
  bf16* lA = As + r0 * 32 + c0;
  bf16* lBa = Ba + r0 * 32 + c0;
  bf16* lBg = Bg + r0 * 32 + c0;

  for (int k0 = 0; k0 < K; k0 += 64) {
    __syncthreads();
    glds16(Ap + k0, lA);
    glds16(Ap + k0 + (size_t)64 * K, lA + 64 * 32);
    glds16(Ap + k0 + 32, lA + 128 * 32);
    glds16(Ap + k0 + 32 + (size_t)64 * K, lA + 192 * 32);
    glds16(Bap + k0, lBa);
    glds16(Bap + k0 + 32, lBa + 64 * 32);
    glds16(Bgp + k0, lBg);
    glds16(Bgp + k0 + 32, lBg + 64 * 32);
    __syncthreads();
#pragma unroll
    for (int kh = 0; kh < 2; ++kh) {
      const bf16* Asp = As + kh * 128 * 32;
      const bf16* Bap_s = Ba + kh * 64 * 32;
      const bf16* Bgp_s = Bg + kh * 64 * 32;
      bf16x8 af[4], ba[2], bg[2];
#pragma unroll
      for (int i = 0; i < 4; ++i)
        af[i] = *(const bf16x8*)(Asp + (mw + i * 16 + l16) * 32 + quad * 8);
#pragma unroll
      for (int j = 0; j < 2; ++j) {
        ba[j] = *(const bf16x8*)(Bap_s + (nw + j * 16 + l16) * 32 + quad * 8);
        bg[j] = *(const bf16x8*)(Bgp_s + (nw + j * 16 + l16) * 32 + quad * 8);
      }
#pragma unroll
      for (int i = 0; i < 4; ++i)
#pragma unroll
        for (int j = 0; j < 2; ++j) {
          aa[i][j] = __builtin_amdgcn_mfma_f32_16x16x32_bf16(af[i], ba[j], aa[i][j], 0, 0, 0);
          ag[i][j] = __builtin_amdgcn_mfma_f32_16x16x32_bf16(af[i], bg[j], ag[i][j], 0, 0, 0);
        }
    }
  }

#pragma unroll
  for (int i = 0; i < 4; ++i) {
    const int rbase = m0 + mw + i * 16 + quad * 4;
#pragma unroll
    for (int j = 0; j < 2; ++j) {
      const int col = n0 + nw + j * 16 + l16;
      const float ba_v = bias[col];
      const float bg_v = bias[N + col];
#pragma unroll
      for (int r = 0; r < 4; ++r) {
        float av = aa[i][j][r] + ba_v;
        float gv = ag[i][j][r] + bg_v;
        float ge = 0.5f * gv * (1.0f + erff(gv * 0.70710678118654752f));
        Cb[(size_t)(rbase + r) * N + col] = (bf16)(av * ge);
      }
    }
  }
}

// ---------------- flash attention, fixed-max softmax, 128 Q-rows/block ----------------
// Wave handles 32 Q-rows as two 16-row MFMA groups; K/V frag reads shared across groups.
__global__ __launch_bounds__(256) void k_attn(const bf16* __restrict__ Qp, int qstride,
                                              const bf16* __restrict__ Kp, int kstride,
                                              const bf16* __restrict__ VTp,
                                              bf16* __restrict__ Op, int kvlen) {
  const int qt = blockIdx.x * 128;
  const int hd = blockIdx.y;
  const int b = blockIdx.z;
  const int tid = threadIdx.x;
  const int wave = tid >> 6, lane = tid & 63;
  const int quad = lane >> 4, l16 = lane & 15;

  __shared__ __align__(16) bf16 Ks[64 * 64];      // [key][d]
  __shared__ __align__(16) bf16 Vs[64 * 64];      // [d][key]
  __shared__ __align__(16) bf16 Ps[4][32 * 72];   // per-wave P, 32 rows, stride 72

  // Q A-frags for both groups, 1/8 folded in
  bf16x8 qf[2][2];
#pragma unroll
  for (int g = 0; g < 2; ++g) {
    const bf16* qrow = Qp + (size_t)(b * cS + qt + wave * 32 + g * 16 + l16) * qstride + hd * 64;
#pragma unroll
    for (int c = 0; c < 2; ++c) {
      bf16x8 raw = *(const bf16x8*)(qrow + c * 32 + quad * 8);
#pragma unroll
      for (int e = 0; e < 8; ++e) qf[g][c][e] = (bf16)((float)raw[e] * 0.125f);
    }
  }

  float l_part[2][4] = {{0.f, 0.f, 0.f, 0.f}, {0.f, 0.f, 0.f, 0.f}};
  f32x4 o_acc[2][4];
#pragma unroll
  for (int g = 0; g < 2; ++g)
#pragma unroll
    for (int n = 0; n < 4; ++n) o_acc[g][n] = (f32x4){0.f, 0.f, 0.f, 0.f};

  // staging: lane i -> row 16w + (i>>3), col (i&7)*8; LDS byte = 2048w + 16i  ✓ law
  const int lrow = wave * 16 + (lane >> 3);
  const int lcol = (lane & 7) * 8;
  const bf16* kbase = Kp + (size_t)(b * kvlen + lrow) * kstride + hd * 64 + lcol;
  const bf16* vbase = VTp + ((size_t)((b * 16 + hd) * 64 + lrow)) * kvlen + lcol;
  bf16* lk = Ks + lrow * 64 + lcol;
  bf16* lv = Vs + lrow * 64 + lcol;

  for (int kt = 0; kt < kvlen; kt += 64) {
    __syncthreads();
    const bf16* kg = kbase + (size_t)kt * kstride;
    glds16(kg, lk);
    glds16(kg + (size_t)8 * kstride, lk + 8 * 64);
    glds16(vbase + kt, lv);
    glds16(vbase + kt + (size_t)8 * kvlen, lv + 8 * 64);
    __syncthreads();

    // scores: K-frags read once, used by both Q-groups
    f32x4 s[2][4];
#pragma unroll
    for (int g = 0; g < 2; ++g)
#pragma unroll
      for (int t = 0; t < 4; ++t) s[g][t] = (f32x4){0.f, 0.f, 0.f, 0.f};
#pragma unroll
    for (int t = 0; t < 4; ++t)
#pragma unroll
      for (int c = 0; c < 2; ++c) {
        bf16x8 kf = *(const bf16x8*)(Ks + (t * 16 + l16) * 64 + c * 32 + quad * 8);
#pragma unroll
        for (int g = 0; g < 2; ++g)
          s[g][t] = __builtin_amdgcn_mfma_f32_16x16x32_bf16(qf[g][c], kf, s[g][t], 0, 0, 0);
      }

    // fixed-max softmax
#pragma unroll
    for (int g = 0; g < 2; ++g)
#pragma unroll
      for (int t = 0; t < 4; ++t)
#pragma unroll
        for (int r = 0; r < 4; ++r) {
          float p = __expf(s[g][t][r]);
          Ps[wave][(g * 16 + quad * 4 + r) * 72 + t * 16 + l16] = (bf16)p;
          l_part[g][r] += p;
        }

    // PV: V-frags read once, used by both groups
    bf16x8 pf[2][2];
#pragma unroll
    for (int g = 0; g < 2; ++g)
#pragma unroll
      for (int c = 0; c < 2; ++c)
        pf[g][c] = *(const bf16x8*)(&Ps[wave][(g * 16 + l16) * 72 + c * 32 + quad * 8]);
#pragma unroll
    for (int n = 0; n < 4; ++n)
#pragma unroll
      for (int c = 0; c < 2; ++c) {
        bf16x8 vf = *(const bf16x8*)(Vs + (n * 16 + l16) * 64 + c * 32 + quad * 8);
#pragma unroll
        for (int g = 0; g < 2; ++g)
          o_acc[g][n] = __builtin_amdgcn_mfma_f32_16x16x32_bf16(pf[g][c], vf, o_acc[g][n], 0, 0, 0);
      }
  }

#pragma unroll
  for (int g = 0; g < 2; ++g) {
    float rl[4];
#pragma unroll
    for (int r = 0; r < 4; ++r) {
      float v = l_part[g][r];
      v += __shfl_xor(v, 1);
      v += __shfl_xor(v, 2);
      v += __shfl_xor(v, 4);
      v += __shfl_xor(v, 8);
      rl[r] = 1.f / v;
    }
#pragma unroll
    for (int n = 0; n < 4; ++n)
#pragma unroll
      for (int r = 0; r < 4; ++r) {
        const int srow = qt + wave * 32 + g * 16 + quad * 4 + r;
        const int d = n * 16 + l16;
        Op[(size_t)(b * cS + srow) * 1024 + hd * 64 + d] = (bf16)(o_acc[g][n][r] * rl[r]);
      }
  }
}

// ---------------- launch ----------------
extern "C" void kernel_launch(void* const* d_in, const int* in_sizes, int n_in,
                              void* d_out, int out_size, void* d_ws, size_t ws_size,
                              hipStream_t stream) {
  const float* x    = (const float*)d_in[0];
  const float* tt   = (const float*)d_in[1];
  const float* ctx  = (const float*)d_in[2];
  const float* a1wq = (const float*)d_in[3];
  const float* a1wk = (const float*)d_in[4];
  const float* a1wv = (const float*)d_in[5];
  const float* a1wo = (const float*)d_in[6];
  const float* a1bo = (const float*)d_in[7];
  const float* a2wq = (const float*)d_in[8];
  const float* a2wk = (const float*)d_in[9];
  const float* a2wv = (const float*)d_in[10];
  const float* a2wo = (const float*)d_in[11];
  const float* a2bo = (const float*)d_in[12];
  const float* fw1  = (const float*)d_in[13];
  const float* fb1  = (const float*)d_in[14];
  const float* fw2  = (const float*)d_in[15];
  const float* fb2  = (const float*)d_in[16];
  const float* n1w  = (const float*)d_in[17];
  const float* n1b  = (const float*)d_in[18];
  const float* n2w  = (const float*)d_in[19];
  const float* n2b  = (const float*)d_in[20];
  const float* n3w  = (const float*)d_in[21];
  const float* n3b  = (const float*)d_in[22];

  char* ws = (char*)d_ws;
  const size_t MB = 1ull << 20;
  bf16* wqkv1 = (bf16*)(ws + 0 * MB);              // [3072,1024], 6 MB
  bf16* wto1  = (bf16*)(ws + 6 * MB);
  bf16* wtq2  = (bf16*)(ws + 8 * MB);
  bf16* wkv2w = (bf16*)(ws + 10 * MB);             // [2048,1024], 4 MB
  bf16* wto2  = (bf16*)(ws + 14 * MB);
  bf16* wtf1  = (bf16*)(ws + 16 * MB);             // [8192,1024], 16 MB
  bf16* wtf2  = (bf16*)(ws + 32 * MB);             // [1024,4096], 8 MB
  float* emb1 = (float*)(ws + 40 * MB);
  float* emb2 = (float*)(ws + 40 * MB + 65536);
  float* emb3 = (float*)(ws + 40 * MB + 131072);
  bf16* ctxb  = (bf16*)(ws + 40 * MB + 262144);    // [512,1024], 1 MB
  float* xres = (float*)(ws + 42 * MB);            // fp32 residual, 16 MB
  bf16* h     = (bf16*)(ws + 58 * MB);             // 8 MB
  bf16* ao    = h;
  bf16* qkv   = (bf16*)(ws + 66 * MB);             // [4096,3072], 24 MB
  bf16* q2    = qkv;
  bf16* vT1   = (bf16*)(ws + 90 * MB);             // [32*64,2048], 8 MB
  bf16* kv2   = (bf16*)(ws + 0 * MB);              // [512,2048], 2 MB
  bf16* vT2   = (bf16*)(ws + 2 * MB);              // [32*64,256], 1 MB
  bf16* g     = (bf16*)(ws + 66 * MB);             // [4096,4096], 32 MB
  float* out  = (float*)d_out;

  const dim3 blk(256);

  k_transpose<<<dim3(16, 16), blk, 0, stream>>>(a1wq, wqkv1, 1024, 1024);
  k_transpose<<<dim3(16, 16), blk, 0, stream>>>(a1wk, wqkv1 + 1024 * 1024, 1024, 1024);
  k_transpose<<<dim3(16, 16), blk, 0, stream>>>(a1wv, wqkv1 + 2 * 1024 * 1024, 1024, 1024);
  k_transpose<<<dim3(16, 16), blk, 0, stream>>>(a1wo, wto1, 1024, 1024);
  k_transpose<<<dim3(16, 16), blk, 0, stream>>>(a2wq, wtq2, 1024, 1024);
  k_transpose<<<dim3(16, 16), blk, 0, stream>>>(a2wk, wkv2w, 1024, 1024);
  k_transpose<<<dim3(16, 16), blk, 0, stream>>>(a2wv, wkv2w + 1024 * 1024, 1024, 1024);
  k_transpose<<<dim3(16, 16), blk, 0, stream>>>(a2wo, wto2, 1024, 1024);
  k_transpose<<<dim3(128, 16), blk, 0, stream>>>(fw1, wtf1, 1024, 8192);
  k_transpose<<<dim3(16, 64), blk, 0, stream>>>(fw2, wtf2, 4096, 1024);

  k_emb<<<32, blk, 0, stream>>>(tt, n1w, n1b, emb1);
  k_emb<<<32, blk, 0, stream>>>(tt, n2w, n2b, emb2);
  k_emb<<<32, blk, 0, stream>>>(tt, n3w, n3b, emb3);
  k_f2b<<<512, blk, 0, stream>>>(ctx, ctxb);

  // ---- block 1: self-attention ----
  k_adaln<<<4096, blk, 0, stream>>>(x, emb1, h);
  k_gemm_t<128><<<dim3(24, 32), blk, 0, stream>>>(h, wqkv1, qkv, nullptr, nullptr, nullptr, 4096, 3072, 1024);
  k_vt<<<dim3(32, 32), blk, 0, stream>>>(qkv + 2048, 3072, vT1, 2048);
  k_attn<<<dim3(16, 16, 2), blk, 0, stream>>>(qkv, 3072, qkv + 1024, 3072, vT1, ao, 2048);
  k_gemm_t<64><<<dim3(16, 32), blk, 0, stream>>>(ao, wto1, nullptr, xres, a1bo, x, 4096, 1024, 1024);

  // ---- block 2: cross-attention ----
  k_adaln<<<4096, blk, 0, stream>>>(xres, emb2, h);
  k_gemm_t<64><<<dim3(16, 32), blk, 0, stream>>>(h, wtq2, q2, nullptr, nullptr, nullptr, 4096, 1024, 1024);
  k_gemm_t<128><<<dim3(16, 4), blk, 0, stream>>>(ctxb, wkv2w, kv2, nullptr, nullptr, nullptr, 512, 2048, 1024);
  k_vt<<<dim3(4, 32), blk, 0, stream>>>(kv2 + 1024, 2048, vT2, 256);
  k_attn<<<dim3(16, 16, 2), blk, 0, stream>>>(q2, 1024, kv2, 2048, vT2, ao, 256);
  k_gemm_t<64><<<dim3(16, 32), blk, 0, stream>>>(ao, wto2, nullptr, xres, a2bo, xres, 4096, 1024, 1024);

  // ---- block 3: gated-GELU FFN ----
  k_adaln<<<4096, blk, 0, stream>>>(xres, emb3, h);
  k_gemm_glu<<<dim3(64, 32), blk, 0, stream>>>(h, wtf1, fb1, g, 4096, 4096, 1024);
  k_gemm_t<64><<<dim3(16, 32), blk, 0, stream>>>(g, wtf2, nullptr, out, fb2, xres, 4096, 1024, 4096);
}

// Round 7
// 641.389 us; speedup vs baseline: 1.4517x; 1.0583x over previous
//
#include <hip/hip_runtime.h>
#include <hip/hip_bf16.h>
#include <math.h>
#include <stdint.h>

typedef __bf16 bf16;
typedef __attribute__((ext_vector_type(8))) __bf16 bf16x8;
typedef __attribute__((ext_vector_type(4))) __bf16 bf16x4;
typedef __attribute__((ext_vector_type(4))) float f32x4;
typedef __attribute__((ext_vector_type(16))) float f32x16;

static constexpr int cB = 2, cS = 2048, cCTX = 256, cD = 1024, cH = 16, cDH = 64, cDFF = 4096;

// async 16B global->LDS. HW semantics: dest = wave-uniform base + lane*16.
// Every call site MUST have lane i's lds ptr == base + 16*i bytes.
__device__ __forceinline__ void glds16(const bf16* g, bf16* l) {
  __builtin_amdgcn_global_load_lds(
      (const __attribute__((address_space(1))) void*)g,
      (__attribute__((address_space(3))) void*)l, 16, 0, 0);
}

// ---------------- batched transpose+convert: 8x fp32 [1024,1024] -> bf16 [1024,1024]^T ----------------
struct T8 { const float* s[8]; };
__global__ __launch_bounds__(256) void k_transpose8(T8 args, bf16* __restrict__ out) {
  __shared__ bf16 tile[64][66];
  const int n0 = blockIdx.x * 64, k0 = blockIdx.y * 64;
  const int z = blockIdx.z;
  const float* in = args.s[z];
  bf16* dst_base = out + (size_t)z * 1024 * 1024;
  const int t = threadIdx.x;
  const int r = t >> 2, cb = (t & 3) * 16;
  const float* src = in + (size_t)(k0 + r) * 1024 + n0 + cb;
#pragma unroll
  for (int q4 = 0; q4 < 4; ++q4) {
    f32x4 v = *(const f32x4*)(src + q4 * 4);
#pragma unroll
    for (int e = 0; e < 4; ++e) tile[r][cb + q4 * 4 + e] = (bf16)v[e];
  }
  __syncthreads();
  bf16* dst = dst_base + (size_t)(n0 + r) * 1024 + k0 + cb;
  bf16x8 o0, o1;
#pragma unroll
  for (int e = 0; e < 8; ++e) { o0[e] = tile[cb + e][r]; o1[e] = tile[cb + 8 + e][r]; }
  *(bf16x8*)(dst) = o0;
  *(bf16x8*)(dst + 8) = o1;
}

// ---------------- transpose+convert: fp32 [K,N] -> bf16 [N,K] (for ff weights) ----------------
__global__ __launch_bounds__(256) void k_transpose(const float* __restrict__ in,
                                                   bf16* __restrict__ out, int K, int N) {
  __shared__ bf16 tile[64][66];
  const int n0 = blockIdx.x * 64, k0 = blockIdx.y * 64;
  const int t = threadIdx.x;
  const int r = t >> 2, cb = (t & 3) * 16;
  const float* src = in + (size_t)(k0 + r) * N + n0 + cb;
#pragma unroll
  for (int q4 = 0; q4 < 4; ++q4) {
    f32x4 v = *(const f32x4*)(src + q4 * 4);
#pragma unroll
    for (int e = 0; e < 4; ++e) tile[r][cb + q4 * 4 + e] = (bf16)v[e];
  }
  __syncthreads();
  bf16* dst = out + (size_t)(n0 + r) * K + k0 + cb;
  bf16x8 o0, o1;
#pragma unroll
  for (int e = 0; e < 8; ++e) { o0[e] = tile[cb + e][r]; o1[e] = tile[cb + 8 + e][r]; }
  *(bf16x8*)(dst) = o0;
  *(bf16x8*)(dst + 8) = o1;
}

// ---------------- V transpose -> VT[(b*16+h)*64+d][kvlen] ----------------
__global__ __launch_bounds__(256) void k_vt(const bf16* __restrict__ V, int vstride,
                                            bf16* __restrict__ VT, int kvlen) {
  __shared__ bf16 tile[64][72];
  const int kt = blockIdx.x * 64, bh = blockIdx.y;
  const int b = bh >> 4, h = bh & 15;
  const int t = threadIdx.x, r = t >> 2, cb = (t & 3) * 16;
  const bf16* src = V + (size_t)(b * kvlen + kt + r) * vstride + h * 64 + cb;
  bf16x8 a0 = *(const bf16x8*)src;
  bf16x8 a1 = *(const bf16x8*)(src + 8);
#pragma unroll
  for (int e = 0; e < 8; ++e) { tile[r][cb + e] = a0[e]; tile[r][cb + 8 + e] = a1[e]; }
  __syncthreads();
  bf16* dst = VT + ((size_t)bh * 64 + r) * kvlen + kt + cb;
  bf16x8 o0, o1;
#pragma unroll
  for (int e = 0; e < 8; ++e) { o0[e] = tile[cb + e][r]; o1[e] = tile[cb + 8 + e][r]; }
  *(bf16x8*)(dst) = o0;
  *(bf16x8*)(dst + 8) = o1;
}

// ---------------- fp32 -> bf16 elementwise ----------------
__global__ __launch_bounds__(256) void k_f2b(const float* __restrict__ in, bf16* __restrict__ out) {
  const int base = (blockIdx.x * 256 + threadIdx.x) * 4;
  f32x4 v = *(const f32x4*)(in + base);
  bf16x4 o;
#pragma unroll
  for (int e = 0; e < 4; ++e) o[e] = (bf16)v[e];
  *(bf16x4*)(out + base) = o;
}

// ---------------- merged emb: emb_i = t @ W_i + b_i -> fp32 [3][2,2048] ----------------
struct EmbArgs { const float* w0; const float* w1; const float* w2;
                 const float* b0; const float* b1; const float* b2; };
__global__ __launch_bounds__(256) void k_emb3(const float* __restrict__ t, EmbArgs ea,
                                              float* __restrict__ emb) {
  const int which = blockIdx.y;
  const float* w = which == 0 ? ea.w0 : (which == 1 ? ea.w1 : ea.w2);
  const float* bias = which == 0 ? ea.b0 : (which == 1 ? ea.b1 : ea.b2);
  float* dst = emb + which * 4096;
  const int jj = threadIdx.x & 63;
  const int j = blockIdx.x * 64 + jj;
  const int kg = threadIdx.x >> 6;
  float a0 = 0.f, a1 = 0.f;
  for (int k = kg * 256; k < kg * 256 + 256; ++k) {
    float wv = w[(size_t)k * 2048 + j];
    a0 += t[k] * wv;
    a1 += t[1024 + k] * wv;
  }
  __shared__ float s0[4][64], s1[4][64];
  s0[kg][jj] = a0;
  s1[kg][jj] = a1;
  __syncthreads();
  if (threadIdx.x < 64) {
    dst[j] = s0[0][jj] + s0[1][jj] + s0[2][jj] + s0[3][jj] + bias[j];
    dst[2048 + j] = s1[0][jj] + s1[1][jj] + s1[2][jj] + s1[3][jj] + bias[j];
  }
}

// ---------------- AdaLN ----------------
__global__ __launch_bounds__(256) void k_adaln(const float* __restrict__ xres,
                                               const float* __restrict__ emb,
                                               bf16* __restrict__ h) {
  const int token = blockIdx.x;
  const int b = token >> 11;
  const float* x = xres + (size_t)token * 1024;
  const float* sc = emb + b * 2048;
  const int t = threadIdx.x;
  float v[4], s = 0.f, sq = 0.f;
#pragma unroll
  for (int i = 0; i < 4; ++i) {
    float u = x[t + 256 * i];
    v[i] = u; s += u; sq += u * u;
  }
#pragma unroll
  for (int off = 1; off < 64; off <<= 1) {
    s += __shfl_xor(s, off);
    sq += __shfl_xor(sq, off);
  }
  __shared__ float ss[4], ssq[4];
  const int wave = t >> 6;
  if ((t & 63) == 0) { ss[wave] = s; ssq[wave] = sq; }
  __syncthreads();
  const float S_ = ss[0] + ss[1] + ss[2] + ss[3];
  const float SQ = ssq[0] + ssq[1] + ssq[2] + ssq[3];
  const float mean = S_ * (1.f / 1024.f);
  const float var = SQ * (1.f / 1024.f) - mean * mean;
  const float rstd = rsqrtf(var + 1e-5f);
#pragma unroll
  for (int i = 0; i < 4; ++i) {
    const int c = t + 256 * i;
    float val = (v[i] - mean) * rstd * (1.f + sc[c]) + sc[1024 + c];
    h[(size_t)token * 1024 + c] = (bf16)val;
  }
}

// ---------------- GEMM (32x32x16 MFMA): C[M,N] = A[M,K] @ Bt[N,K]^T (+bias)(+res) ----------------
// Tile 128 x TN, BK=64 as two 32-col panels (LDS geometry identical to R6 / m97 law).
// A-frag: row=lane&31, k=(lane>>5)*8+e. C/D: col=lane&31, row=(reg&3)+8*(reg>>2)+4*(lane>>5) [m74/m101].
template <int TN>
__global__ __launch_bounds__(256) void k_gemm_t(const bf16* __restrict__ A,
                                                const bf16* __restrict__ Bt,
                                                bf16* Cb, float* Cf,
                                                const float* __restrict__ bias,
                                                const float* res,
                                                int M, int N, int K) {
  constexpr int CJ = TN / 64;  // 32-col MFMA tiles per wave (1 or 2)
  __shared__ bf16 As[2 * 128 * 32];
  __shared__ bf16 Bs[2 * TN * 32];
  const int m0 = blockIdx.y * 128, n0 = blockIdx.x * TN;
  const int tid = threadIdx.x;
  const int wave = tid >> 6, lane = tid & 63;
  const int l31 = lane & 31, hi8 = (lane >> 5) * 8;
  const int mw = (wave >> 1) * 64, nw = (wave & 1) * (TN / 2);
  f32x16 acc[2][CJ];
#pragma unroll
  for (int i = 0; i < 2; ++i)
#pragma unroll
    for (int j = 0; j < CJ; ++j) acc[i][j] = (f32x16)(0.f);

  const int r0 = tid >> 2, c0 = (tid & 3) << 3;
  const bf16* Ap = A + (size_t)(m0 + r0) * K + c0;
  const bf16* Bp = Bt + (size_t)(n0 + r0) * K + c0;
  bf16* lA = As + r0 * 32 + c0;
  bf16* lB = Bs + r0 * 32 + c0;

  for (int k0 = 0; k0 < K; k0 += 64) {
    __syncthreads();
    glds16(Ap + k0, lA);
    glds16(Ap + k0 + (size_t)64 * K, lA + 64 * 32);
    glds16(Ap + k0 + 32, lA + 128 * 32);
    glds16(Ap + k0 + 32 + (size_t)64 * K, lA + 192 * 32);
    glds16(Bp + k0, lB);
    if (TN == 128) glds16(Bp + k0 + (size_t)64 * K, lB + 64 * 32);
    glds16(Bp + k0 + 32, lB + TN * 32);
    if (TN == 128) glds16(Bp + k0 + 32 + (size_t)64 * K, lB + TN * 32 + 64 * 32);
    __syncthreads();
#pragma unroll
    for (int kp = 0; kp < 2; ++kp) {        // 32-col panel
      const bf16* Asp = As + kp * 128 * 32;
      const bf16* Bsp = Bs + kp * TN * 32;
#pragma unroll
      for (int kh = 0; kh < 2; ++kh) {      // 16-k half within panel
        bf16x8 af[2], bfr[CJ];
#pragma unroll
        for (int i = 0; i < 2; ++i)
          af[i] = *(const bf16x8*)(Asp + (mw + i * 32 + l31) * 32 + kh * 16 + hi8);
#pragma unroll
        for (int j = 0; j < CJ; ++j)
          bfr[j] = *(const bf16x8*)(Bsp + (nw + j * 32 + l31) * 32 + kh * 16 + hi8);
#pragma unroll
        for (int i = 0; i < 2; ++i)
#pragma unroll
          for (int j = 0; j < CJ; ++j)
            acc[i][j] = __builtin_amdgcn_mfma_f32_32x32x16_bf16(af[i], bfr[j], acc[i][j], 0, 0, 0);
      }
    }
  }

#pragma unroll
  for (int i = 0; i < 2; ++i) {
    const int rb = m0 + mw + i * 32 + 4 * (lane >> 5);
#pragma unroll
    for (int j = 0; j < CJ; ++j) {
      const int col = n0 + nw + j * 32 + l31;
      const float bv = bias ? bias[col] : 0.f;
#pragma unroll
      for (int reg = 0; reg < 16; ++reg) {
        const int row = rb + (reg & 3) + 8 * (reg >> 2);
        const size_t off = (size_t)row * N + col;
        float v2 = acc[i][j][reg] + bv;
        if (res) v2 += res[off];
        if (Cf) Cf[off] = v2;
        if (Cb) Cb[off] = (bf16)v2;
      }
    }
  }
}

// ---------------- FF1 GEMM + fused GLU (32x32x16 MFMA, N-tile 64) ----------------
__global__ __launch_bounds__(256) void k_gemm_glu(const bf16* __restrict__ A,
                                                  const bf16* __restrict__ Bt,
                                                  const float* __restrict__ bias,
                                                  bf16* __restrict__ Cb,
                                                  int M, int N, int K) {
  __shared__ bf16 As[2 * 128 * 32];
  __shared__ bf16 Ba[2 * 64 * 32];
  __shared__ bf16 Bg[2 * 64 * 32];
  const int m0 = blockIdx.y * 128, n0 = blockIdx.x * 64;
  const int tid = threadIdx.x;
  const int wave = tid >> 6, lane = tid & 63;
  const int l31 = lane & 31, hi8 = (lane >> 5) * 8;
  const int mw = (wave >> 1) * 64, nw = (wave & 1) * 32;
  f32x16 aa[2], ag[2];
#pragma unroll
  for (int i = 0; i < 2; ++i) { aa[i] = (f32x16)(0.f); ag[i] = (f32x16)(0.f); }

  const int r0 = tid >> 2, c0 = (tid & 3) << 3;
  const bf16* Ap = A + (size_t)(m0 + r0) * K + c0;
  const bf16* Bap = Bt + (size_t)(n0 + r0) * K + c0;
  const bf16* Bgp = Bt + (size_t)(N + n0 + r0) * K + c0;
  bf16* lA = As + r0 * 32 + c0;
  bf16* lBa = Ba + r0 * 32 + c0;
  bf16* lBg = Bg + r0 * 32 + c0;

  for (int k0 = 0; k0 < K; k0 += 64) {
    __syncthreads();
    glds16(Ap + k0, lA);
    glds16(Ap + k0 + (size_t)64 * K, lA + 64 * 32);
    glds16(Ap + k0 + 32, lA + 128 * 32);
    glds16(Ap + k0 + 32 + (size_t)64 * K, lA + 192 * 32);
    glds16(Bap + k0, lBa);
    glds16(Bap + k0 + 32, lBa + 64 * 32);
    glds16(Bgp + k0, lBg);
    glds16(Bgp + k0 + 32, lBg + 64 * 32);
    __syncthreads();
#pragma unroll
    for (int kp = 0; kp < 2; ++kp) {
      const bf16* Asp = As + kp * 128 * 32;
      const bf16* Bap_s = Ba + kp * 64 * 32;
      const bf16* Bgp_s = Bg + kp * 64 * 32;
#pragma unroll
      for (int kh = 0; kh < 2; ++kh) {
        bf16x8 af[2], ba, bg;
#pragma unroll
        for (int i = 0; i < 2; ++i)
          af[i] = *(const bf16x8*)(Asp + (mw + i * 32 + l31) * 32 + kh * 16 + hi8);
        ba = *(const bf16x8*)(Bap_s + (nw + l31) * 32 + kh * 16 + hi8);
        bg = *(const bf16x8*)(Bgp_s + (nw + l31) * 32 + kh * 16 + hi8);
#pragma unroll
        for (int i = 0; i < 2; ++i) {
          aa[i] = __builtin_amdgcn_mfma_f32_32x32x16_bf16(af[i], ba, aa[i], 0, 0, 0);
          ag[i] = __builtin_amdgcn_mfma_f32_32x32x16_bf16(af[i], bg, ag[i], 0, 0, 0);
        }
      }
    }
  }

  const int col = n0 + nw + l31;
  const float ba_v = bias[col];
  const float bg_v = bias[N + col];
#pragma unroll
  for (int i = 0; i < 2; ++i) {
    const int rb = m0 + mw + i * 32 + 4 * (lane >> 5);
#pragma unroll
    for (int reg = 0; reg < 16; ++reg) {
      const int row = rb + (reg & 3) + 8 * (reg >> 2);
      float av = aa[i][reg] + ba_v;
      float gv = ag[i][reg] + bg_v;
      float ge = 0.5f * gv * (1.0f + erff(gv * 0.70710678118654752f));
      Cb[(size_t)row * N + col] = (bf16)(av * ge);
    }
  }
}

// ---------------- flash attention, fixed-max softmax, 128 Q-rows/block ----------------
__global__ __launch_bounds__(256) void k_attn(const bf16* __restrict__ Qp, int qstride,
                                              const bf16* __restrict__ Kp, int kstride,
                                              const bf16* __restrict__ VTp,
                                              bf16* __restrict__ Op, int kvlen) {
  const int qt = blockIdx.x * 128;
  const int hd = blockIdx.y;
  const int b = blockIdx.z;
  const int tid = threadIdx.x;
  const int wave = tid >> 6, lane = tid & 63;
  const int quad = lane >> 4, l16 = lane & 15;

  __shared__ __align__(16) bf16 Ks[64 * 64];
  __shared__ __align__(16) bf16 Vs[64 * 64];
  __shared__ __align__(16) bf16 Ps[4][32 * 72];

  bf16x8 qf[2][2];
#pragma unroll
  for (int g = 0; g < 2; ++g) {
    const bf16* qrow = Qp + (size_t)(b * cS + qt + wave * 32 + g * 16 + l16) * qstride + hd * 64;
#pragma unroll
    for (int c = 0; c < 2; ++c) {
      bf16x8 raw = *(const bf16x8*)(qrow + c * 32 + quad * 8);
#pragma unroll
      for (int e = 0; e < 8; ++e) qf[g][c][e] = (bf16)((float)raw[e] * 0.125f);
    }
  }

  float l_part[2][4] = {{0.f, 0.f, 0.f, 0.f}, {0.f, 0.f, 0.f, 0.f}};
  f32x4 o_acc[2][4];
#pragma unroll
  for (int g = 0; g < 2; ++g)
#pragma unroll
    for (int n = 0; n < 4; ++n) o_acc[g][n] = (f32x4){0.f, 0.f, 0.f, 0.f};

  const int lrow = wave * 16 + (lane >> 3);
  const int lcol = (lane & 7) * 8;
  const bf16* kbase = Kp + (size_t)(b * kvlen + lrow) * kstride + hd * 64 + lcol;
  const bf16* vbase = VTp + ((size_t)((b * 16 + hd) * 64 + lrow)) * kvlen + lcol;
  bf16* lk = Ks + lrow * 64 + lcol;
  bf16* lv = Vs + lrow * 64 + lcol;

  for (int kt = 0; kt < kvlen; kt += 64) {
    __syncthreads();
    const bf16* kg = kbase + (size_t)kt * kstride;
    glds16(kg, lk);
    glds16(kg + (size_t)8 * kstride, lk + 8 * 64);
    glds16(vbase + kt, lv);
    glds16(vbase + kt + (size_t)8 * kvlen, lv + 8 * 64);
    __syncthreads();

    f32x4 s[2][4];
#pragma unroll
    for (int g = 0; g < 2; ++g)
#pragma unroll
      for (int t = 0; t < 4; ++t) s[g][t] = (f32x4){0.f, 0.f, 0.f, 0.f};
#pragma unroll
    for (int t = 0; t < 4; ++t)
#pragma unroll
      for (int c = 0; c < 2; ++c) {
        bf16x8 kf = *(const bf16x8*)(Ks + (t * 16 + l16) * 64 + c * 32 + quad * 8);
#pragma unroll
        for (int g = 0; g < 2; ++g)
          s[g][t] = __builtin_amdgcn_mfma_f32_16x16x32_bf16(qf[g][c], kf, s[g][t], 0, 0, 0);
      }

#pragma unroll
    for (int g = 0; g < 2; ++g)
#pragma unroll
      for (int t = 0; t < 4; ++t)
#pragma unroll
        for (int r = 0; r < 4; ++r) {
          float p = __expf(s[g][t][r]);
          Ps[wave][(g * 16 + quad * 4 + r) * 72 + t * 16 + l16] = (bf16)p;
          l_part[g][r] += p;
        }

    bf16x8 pf[2][2];
#pragma unroll
    for (int g = 0; g < 2; ++g)
#pragma unroll
      for (int c = 0; c < 2; ++c)
        pf[g][c] = *(const bf16x8*)(&Ps[wave][(g * 16 + l16) * 72 + c * 32 + quad * 8]);
#pragma unroll
    for (int n = 0; n < 4; ++n)
#pragma unroll
      for (int c = 0; c < 2; ++c) {
        bf16x8 vf = *(const bf16x8*)(Vs + (n * 16 + l16) * 64 + c * 32 + quad * 8);
#pragma unroll
        for (int g = 0; g < 2; ++g)
          o_acc[g][n] = __builtin_amdgcn_mfma_f32_16x16x32_bf16(pf[g][c], vf, o_acc[g][n], 0, 0, 0);
      }
  }

#pragma unroll
  for (int g = 0; g < 2; ++g) {
    float rl[4];
#pragma unroll
    for (int r = 0; r < 4; ++r) {
      float v = l_part[g][r];
      v += __shfl_xor(v, 1);
      v += __shfl_xor(v, 2);
      v += __shfl_xor(v, 4);
      v += __shfl_xor(v, 8);
      rl[r] = 1.f / v;
    }
#pragma unroll
    for (int n = 0; n < 4; ++n)
#pragma unroll
      for (int r = 0; r < 4; ++r) {
        const int srow = qt + wave * 32 + g * 16 + quad * 4 + r;
        const int d = n * 16 + l16;
        Op[(size_t)(b * cS + srow) * 1024 + hd * 64 + d] = (bf16)(o_acc[g][n][r] * rl[r]);
      }
  }
}

// ---------------- launch ----------------
extern "C" void kernel_launch(void* const* d_in, const int* in_sizes, int n_in,
                              void* d_out, int out_size, void* d_ws, size_t ws_size,
                              hipStream_t stream) {
  const float* x    = (const float*)d_in[0];
  const float* tt   = (const float*)d_in[1];
  const float* ctx  = (const float*)d_in[2];
  const float* fw1  = (const float*)d_in[13];
  const float* fb1  = (const float*)d_in[14];
  const float* fw2  = (const float*)d_in[15];
  const float* fb2  = (const float*)d_in[16];
  const float* a1bo = (const float*)d_in[7];
  const float* a2bo = (const float*)d_in[12];

  char* ws = (char*)d_ws;
  const size_t MB = 1ull << 20;
  // 8 square transposed weights packed: [q1,k1,v1,o1,q2,k2,v2,o2] x 2 MB
  bf16* wsq   = (bf16*)(ws + 0 * MB);
  bf16* wqkv1 = wsq;                               // mats 0-2
  bf16* wto1  = (bf16*)(ws + 6 * MB);              // mat 3
  bf16* wtq2  = (bf16*)(ws + 8 * MB);              // mat 4
  bf16* wkv2w = (bf16*)(ws + 10 * MB);             // mats 5-6
  bf16* wto2  = (bf16*)(ws + 14 * MB);             // mat 7
  bf16* wtf1  = (bf16*)(ws + 16 * MB);             // [8192,1024], 16 MB
  bf16* wtf2  = (bf16*)(ws + 32 * MB);             // [1024,4096], 8 MB
  float* emb  = (float*)(ws + 40 * MB);            // 3 x [2,2048]
  float* emb1 = emb, *emb2 = emb + 4096, *emb3 = emb + 8192;
  bf16* ctxb  = (bf16*)(ws + 40 * MB + 262144);    // [512,1024], 1 MB
  float* xres = (float*)(ws + 42 * MB);            // fp32 residual, 16 MB
  bf16* h     = (bf16*)(ws + 58 * MB);             // 8 MB
  bf16* ao    = h;
  bf16* qkv   = (bf16*)(ws + 66 * MB);             // [4096,3072], 24 MB
  bf16* q2    = qkv;
  bf16* vT1   = (bf16*)(ws + 90 * MB);             // [32*64,2048], 8 MB
  bf16* kv2   = (bf16*)(ws + 0 * MB);              // [512,2048], 2 MB (aliases dead mats 0-1)
  bf16* vT2   = (bf16*)(ws + 2 * MB);              // [32*64,256], 1 MB (aliases dead mat 1)
  bf16* g     = (bf16*)(ws + 66 * MB);             // [4096,4096], 32 MB
  float* out  = (float*)d_out;

  const dim3 blk(256);

  T8 t8;
  t8.s[0] = (const float*)d_in[3];   // a1wq
  t8.s[1] = (const float*)d_in[4];   // a1wk
  t8.s[2] = (const float*)d_in[5];   // a1wv
  t8.s[3] = (const float*)d_in[6];   // a1wo
  t8.s[4] = (const float*)d_in[8];   // a2wq
  t8.s[5] = (const float*)d_in[9];   // a2wk
  t8.s[6] = (const float*)d_in[10];  // a2wv
  t8.s[7] = (const float*)d_in[11];  // a2wo
  k_transpose8<<<dim3(16, 16, 8), blk, 0, stream>>>(t8, wsq);
  k_transpose<<<dim3(128, 16), blk, 0, stream>>>(fw1, wtf1, 1024, 8192);
  k_transpose<<<dim3(16, 64), blk, 0, stream>>>(fw2, wtf2, 4096, 1024);

  EmbArgs ea;
  ea.w0 = (const float*)d_in[17]; ea.b0 = (const float*)d_in[18];
  ea.w1 = (const float*)d_in[19]; ea.b1 = (const float*)d_in[20];
  ea.w2 = (const float*)d_in[21]; ea.b2 = (const float*)d_in[22];
  k_emb3<<<dim3(32, 3), blk, 0, stream>>>(tt, ea, emb);
  k_f2b<<<512, blk, 0, stream>>>(ctx, ctxb);

  // ---- block 1: self-attention ----
  k_adaln<<<4096, blk, 0, stream>>>(x, emb1, h);
  k_gemm_t<128><<<dim3(24, 32), blk, 0, stream>>>(h, wqkv1, qkv, nullptr, nullptr, nullptr, 4096, 3072, 1024);
  k_vt<<<dim3(32, 32), blk, 0, stream>>>(qkv + 2048, 3072, vT1, 2048);
  k_attn<<<dim3(16, 16, 2), blk, 0, stream>>>(qkv, 3072, qkv + 1024, 3072, vT1, ao, 2048);
  k_gemm_t<64><<<dim3(16, 32), blk, 0, stream>>>(ao, wto1, nullptr, xres, a1bo, x, 4096, 1024, 1024);

  // ---- block 2: cross-attention ----
  k_adaln<<<4096, blk, 0, stream>>>(xres, emb2, h);
  k_gemm_t<64><<<dim3(16, 32), blk, 0, stream>>>(h, wtq2, q2, nullptr, nullptr, nullptr, 4096, 1024, 1024);
  k_gemm_t<128><<<dim3(16, 4), blk, 0, stream>>>(ctxb, wkv2w, kv2, nullptr, nullptr, nullptr, 512, 2048, 1024);
  k_vt<<<dim3(4, 32), blk, 0, stream>>>(kv2 + 1024, 2048, vT2, 256);
  k_attn<<<dim3(16, 16, 2), blk, 0, stream>>>(q2, 1024, kv2, 2048, vT2, ao, 256);
  k_gemm_t<64><<<dim3(16, 32), blk, 0, stream>>>(ao, wto2, nullptr, xres, a2bo, xres, 4096, 1024, 1024);

  // ---- block 3: gated-GELU FFN ----
  k_adaln<<<4096, blk, 0, stream>>>(xres, emb3, h);
  k_gemm_glu<<<dim3(64, 32), blk, 0, stream>>>(h, wtf1, fb1, g, 4096, 4096, 1024);
  k_gemm_t<64><<<dim3(16, 32), blk, 0, stream>>>(g, wtf2, nullptr, out, fb2, xres, 4096, 1024, 4096);
}